// Round 8
// baseline (130.044 us; speedup 1.0000x reference)
//
#include <hip/hip_runtime.h>
#include <math.h>

typedef unsigned short ushort_t;
typedef __attribute__((ext_vector_type(8))) short short8;
typedef __attribute__((ext_vector_type(4))) float f32x4;

__device__ inline unsigned bfpair(float lo, float hi) {
  unsigned r;
  asm("v_cvt_pk_bf16_f32 %0, %1, %2" : "=v"(r) : "v"(lo), "v"(hi));
  return r;
}
__device__ inline ushort_t bf16of(float v) { return (ushort_t)(bfpair(v, v) & 0xffffu); }
__device__ inline void permswap32(unsigned &a, unsigned &b) {
  asm("v_permlane32_swap_b32 %0, %1" : "+v"(a), "+v"(b));
}
__device__ inline void permswap16(unsigned &a, unsigned &b) {
  asm("v_permlane16_swap_b32 %0, %1" : "+v"(a), "+v"(b));
}

// ---------------- transpose + convert: W[K][N] f32 -> Wt[N][K] bf16 ----------------
__global__ __launch_bounds__(256) void transpose_bf16_k(
    const float* __restrict__ W, ushort_t* __restrict__ Wt, int K, int N)
{
  __shared__ float Ls[32][33];
  const int t = threadIdx.x;
  const int n0 = blockIdx.x * 32, k0 = blockIdx.y * 32;
  const int tx = t & 31, tyb = t >> 5;
  #pragma unroll
  for (int s = 0; s < 4; ++s) {
    const int k = tyb + s * 8;
    Ls[k][tx] = W[(size_t)(k0 + k) * N + n0 + tx];
  }
  __syncthreads();
  #pragma unroll
  for (int s = 0; s < 2; ++s) {
    const int idx = t + 256 * s;
    const int n = idx >> 4, kk = (idx & 15) * 2;
    const unsigned pk = bfpair(Ls[kk][n], Ls[kk + 1][n]);
    *(unsigned*)&Wt[(size_t)(n0 + n) * K + k0 + kk] = pk;
  }
}

// ---------------- pack QKV weights: WqkvT[80][64] bf16 ----------------
__global__ __launch_bounds__(256) void prep_qkvw_k(
    const float* __restrict__ Wq, const float* __restrict__ Wk,
    const float* __restrict__ Wv, ushort_t* __restrict__ WqkvT)
{
  for (int e = threadIdx.x; e < 80 * 64; e += 256) {
    const int j = e >> 6, k = e & 63;
    float v;
    if (j < 8)       v = Wq[k * 8 + j];
    else if (j < 16) v = Wk[k * 8 + (j - 8)];
    else             v = Wv[k * 64 + (j - 16)];
    WqkvT[e] = bf16of(v);
  }
}

// ---------------- split-K bf16 MFMA GEMM + bias + relu ----------------
// BM=16 rows/block. Waves: w = kw*NW + nw; kw owns K-segment kw*KSEG..,
// nw owns cols nw*NT*16... Partials merged via LDS. grid = M/16.
// HW-verified maps: A-frag lane(g,ln): A[m=ln][k=8g+i]; B-frag: Wt[n][k=8g+i];
// D lane(g,ln) reg r: (row=4g+r, col=ln).
template<int K, int KSEG, int N, int NW, int NT, bool A_FP32, int OMODE>
__global__ __launch_bounds__((K/KSEG)*NW*64) void gemm_splitk(
    const void* __restrict__ Ap, const ushort_t* __restrict__ Wt,
    const float* __restrict__ bias, void* __restrict__ C0, void* __restrict__ C1)
{
  constexpr int KW = K / KSEG;
  const int wave = threadIdx.x >> 6, lane = threadIdx.x & 63;
  const int kw = wave / NW, nw = wave % NW;
  const int ln = lane & 15, g = lane >> 4;
  const int bm0 = blockIdx.x * 16;
  const int n0 = nw * (NT * 16);
  const f32x4 zero4 = {0.f, 0.f, 0.f, 0.f};

  f32x4 acc[NT];
  #pragma unroll
  for (int nt = 0; nt < NT; ++nt) acc[nt] = zero4;

  const float* Af = (const float*)Ap;
  const ushort_t* Ab = (const ushort_t*)Ap;
  const int kbase = kw * KSEG + g * 8;

  #pragma unroll 2
  for (int k0 = 0; k0 < KSEG; k0 += 32) {
    short8 af;
    const size_t abase = (size_t)(bm0 + ln) * K + kbase + k0;
    if (A_FP32) {
      const float4 f0 = *(const float4*)&Af[abase];
      const float4 f1 = *(const float4*)&Af[abase + 4];
      union { unsigned u[4]; short8 s8; } cv;
      cv.u[0] = bfpair(f0.x, f0.y);
      cv.u[1] = bfpair(f0.z, f0.w);
      cv.u[2] = bfpair(f1.x, f1.y);
      cv.u[3] = bfpair(f1.z, f1.w);
      af = cv.s8;
    } else {
      af = *(const short8*)&Ab[abase];
    }
    short8 bfr[NT];
    #pragma unroll
    for (int nt = 0; nt < NT; ++nt)
      bfr[nt] = *(const short8*)&Wt[(size_t)(n0 + nt * 16 + ln) * K + kbase + k0];
    #pragma unroll
    for (int nt = 0; nt < NT; ++nt)
      acc[nt] = __builtin_amdgcn_mfma_f32_16x16x32_bf16(af, bfr[nt], acc[nt], 0, 0, 0);
  }

  __shared__ float red[KW - 1][16][N];
  if (kw > 0) {
    #pragma unroll
    for (int nt = 0; nt < NT; ++nt)
      #pragma unroll
      for (int r = 0; r < 4; ++r)
        red[kw - 1][4 * g + r][n0 + nt * 16 + ln] = acc[nt][r];
  }
  __syncthreads();
  if (kw == 0) {
    #pragma unroll
    for (int nt = 0; nt < NT; ++nt)
      #pragma unroll
      for (int r = 0; r < 4; ++r) {
        const int m = bm0 + 4 * g + r;
        const int n = n0 + nt * 16 + ln;
        float v = acc[nt][r] + bias[n];
        #pragma unroll
        for (int j = 0; j < KW - 1; ++j) v += red[j][4 * g + r][n];
        v = fmaxf(v, 0.f);
        if (OMODE == 0) {
          ((ushort_t*)C0)[(size_t)m * N + n] = bf16of(v);
        } else if (OMODE == 1) {
          ((float*)C0)[(size_t)m * N + n] = v;
        } else {
          ((float*)C0)[(size_t)m * N + n] = v;
          ((ushort_t*)C1)[(size_t)m * N + n] = bf16of(v);
        }
      }
  }
}

// ---------------- plain bf16 MFMA GEMM (for small gemm3) ----------------
template<int K, int N, int NT, bool A_FP32, int OMODE>
__global__ __launch_bounds__(256) void gemm_mfma(
    const void* __restrict__ Ap, const ushort_t* __restrict__ Wt,
    const float* __restrict__ bias, void* __restrict__ C0, void* __restrict__ C1)
{
  const int wave = threadIdx.x >> 6, lane = threadIdx.x & 63;
  const int ln = lane & 15, g = lane >> 4;
  const int bm0 = blockIdx.x * 16;
  const int n0 = wave * (NT * 16);
  const f32x4 zero4 = {0.f, 0.f, 0.f, 0.f};
  f32x4 acc[NT];
  #pragma unroll
  for (int nt = 0; nt < NT; ++nt) acc[nt] = zero4;
  const float* Af = (const float*)Ap;
  const ushort_t* Ab = (const ushort_t*)Ap;
  #pragma unroll 2
  for (int k0 = 0; k0 < K; k0 += 32) {
    short8 af;
    const size_t abase = (size_t)(bm0 + ln) * K + k0 + g * 8;
    if (A_FP32) {
      const float4 f0 = *(const float4*)&Af[abase];
      const float4 f1 = *(const float4*)&Af[abase + 4];
      union { unsigned u[4]; short8 s8; } cv;
      cv.u[0] = bfpair(f0.x, f0.y);
      cv.u[1] = bfpair(f0.z, f0.w);
      cv.u[2] = bfpair(f1.x, f1.y);
      cv.u[3] = bfpair(f1.z, f1.w);
      af = cv.s8;
    } else {
      af = *(const short8*)&Ab[abase];
    }
    short8 bfr[NT];
    #pragma unroll
    for (int nt = 0; nt < NT; ++nt)
      bfr[nt] = *(const short8*)&Wt[(size_t)(n0 + nt * 16 + ln) * K + k0 + g * 8];
    #pragma unroll
    for (int nt = 0; nt < NT; ++nt)
      acc[nt] = __builtin_amdgcn_mfma_f32_16x16x32_bf16(af, bfr[nt], acc[nt], 0, 0, 0);
  }
  #pragma unroll
  for (int nt = 0; nt < NT; ++nt)
    #pragma unroll
    for (int r = 0; r < 4; ++r) {
      const int m = bm0 + 4 * g + r;
      const int n = n0 + nt * 16 + ln;
      float v = acc[nt][r] + bias[n];
      v = fmaxf(v, 0.f);
      if (OMODE == 0) {
        ((ushort_t*)C0)[(size_t)m * N + n] = bf16of(v);
      } else if (OMODE == 1) {
        ((float*)C0)[(size_t)m * N + n] = v;
      } else {
        ((float*)C0)[(size_t)m * N + n] = v;
        ((ushort_t*)C1)[(size_t)m * N + n] = bf16of(v);
      }
    }
}

// ---------------- fused QKV via MFMA ----------------
__global__ __launch_bounds__(64) void qkv_fused_k(
    const ushort_t* __restrict__ H3b, const ushort_t* __restrict__ WqkvT,
    const float* __restrict__ bq, const float* __restrict__ bk, const float* __restrict__ bv,
    ushort_t* __restrict__ Qb, ushort_t* __restrict__ Kb, ushort_t* __restrict__ VT)
{
  const int lane = threadIdx.x;
  const int ln = lane & 15, g = lane >> 4;
  const int q0 = blockIdx.x * 16;
  const f32x4 zero4 = {0.f, 0.f, 0.f, 0.f};
  f32x4 acc[5];
  #pragma unroll
  for (int nt = 0; nt < 5; ++nt) acc[nt] = zero4;
  #pragma unroll
  for (int k0 = 0; k0 < 64; k0 += 32) {
    const short8 af = *(const short8*)&H3b[(size_t)(q0 + ln) * 64 + k0 + g * 8];
    #pragma unroll
    for (int nt = 0; nt < 5; ++nt) {
      const short8 bfr = *(const short8*)&WqkvT[(size_t)(nt * 16 + ln) * 64 + k0 + g * 8];
      acc[nt] = __builtin_amdgcn_mfma_f32_16x16x32_bf16(af, bfr, acc[nt], 0, 0, 0);
    }
  }
  {
    const float b0 = (ln < 8) ? bq[ln] : bk[ln - 8];
    #pragma unroll
    for (int r = 0; r < 4; ++r) {
      const int m = q0 + 4 * g + r;
      const float v = acc[0][r] + b0;
      if (ln < 8) Qb[(size_t)m * 8 + ln] = bf16of(v);
      else        Kb[(size_t)m * 8 + (ln - 8)] = bf16of(v);
    }
  }
  #pragma unroll
  for (int nt = 1; nt < 5; ++nt) {
    const int d = nt * 16 + ln - 16;
    const float b0 = bv[d];
    const float v0 = acc[nt][0] + b0, v1 = acc[nt][1] + b0;
    const float v2 = acc[nt][2] + b0, v3 = acc[nt][3] + b0;
    uint2 o; o.x = bfpair(v0, v1); o.y = bfpair(v2, v3);
    *(uint2*)&VT[(size_t)d * 8192 + q0 + 4 * g] = o;
  }
}

// ---------------- MFMA flash attention + residual (K and V both prefetched) ----------------
__global__ __launch_bounds__(1024) void attn_mfma_k(
    const ushort_t* __restrict__ Qb, const ushort_t* __restrict__ Kb,
    const ushort_t* __restrict__ VT, const float* __restrict__ H3,
    const float* __restrict__ gamma, float* __restrict__ Hatt,
    ushort_t* __restrict__ Hab)
{
  const int wave = threadIdx.x >> 6, lane = threadIdx.x & 63;
  const int q0 = blockIdx.x * 32;
  const int m = lane & 15, g = lane >> 4;
  const f32x4 zero4 = {0.f,0.f,0.f,0.f};

  short8 qf[2] = {{0,0,0,0,0,0,0,0},{0,0,0,0,0,0,0,0}};
  if (lane < 16) {
    qf[0] = *(const short8*)&Qb[(size_t)(q0 + m) * 8];
    qf[1] = *(const short8*)&Qb[(size_t)(q0 + 16 + m) * 8];
  }

  f32x4 acc[2][4];
  #pragma unroll
  for (int qt=0;qt<2;qt++)
    #pragma unroll
    for (int dt=0;dt<4;dt++) acc[qt][dt] = zero4;
  float lsum[2] = {0.f, 0.f};

  const int j0w = wave << 9;   // 512 j per wave
  short8 kc0 = {0,0,0,0,0,0,0,0}, kc1 = {0,0,0,0,0,0,0,0};
  short8 vc[4];
  if (lane < 16) {
    kc0 = *(const short8*)&Kb[(size_t)(j0w + m) * 8];
    kc1 = *(const short8*)&Kb[(size_t)(j0w + 16 + m) * 8];
  }
  {
    const size_t vbase = (size_t)j0w + (size_t)(g << 3);
    #pragma unroll
    for (int dt=0;dt<4;dt++)
      vc[dt] = *(const short8*)&VT[(size_t)(dt*16 + m) * 8192 + vbase];
  }

  #pragma unroll 1
  for (int jc = 0; jc < 512; jc += 32) {
    const int jb = j0w + jc;
    const int jn = (jc + 32 < 512) ? (jb + 32) : j0w;
    // issue next-tile loads first (latency hides under compute below)
    short8 kn0 = {0,0,0,0,0,0,0,0}, kn1 = {0,0,0,0,0,0,0,0};
    short8 vn[4];
    if (lane < 16) {
      kn0 = *(const short8*)&Kb[(size_t)(jn + m) * 8];
      kn1 = *(const short8*)&Kb[(size_t)(jn + 16 + m) * 8];
    }
    const size_t vnbase = (size_t)jn + (size_t)(g << 3);
    #pragma unroll
    for (int dt=0;dt<4;dt++)
      vn[dt] = *(const short8*)&VT[(size_t)(dt*16 + m) * 8192 + vnbase];

    short8 pf[2];
    #pragma unroll
    for (int qt=0;qt<2;qt++) {
      const f32x4 s0 = __builtin_amdgcn_mfma_f32_16x16x32_bf16(kc0, qf[qt], zero4, 0,0,0);
      const f32x4 s1 = __builtin_amdgcn_mfma_f32_16x16x32_bf16(kc1, qf[qt], zero4, 0,0,0);
      const float e00 = __expf(s0[0]), e01 = __expf(s0[1]), e02 = __expf(s0[2]), e03 = __expf(s0[3]);
      const float e10 = __expf(s1[0]), e11 = __expf(s1[1]), e12 = __expf(s1[2]), e13 = __expf(s1[3]);
      lsum[qt] += ((e00+e01)+(e02+e03)) + ((e10+e11)+(e12+e13));
      unsigned X01 = bfpair(e00,e01), X23 = bfpair(e02,e03);
      unsigned Y01 = bfpair(e10,e11), Y23 = bfpair(e12,e13);
      permswap32(X01, Y01); permswap16(X01, Y01);
      permswap32(X23, Y23); permswap16(X23, Y23);
      union { unsigned u[4]; short8 s; } pfu;
      pfu.u[0] = X01;
      pfu.u[1] = X23;
      pfu.u[2] = Y01;
      pfu.u[3] = Y23;
      pf[qt] = pfu.s;
    }
    #pragma unroll
    for (int dt=0;dt<4;dt++) {
      acc[0][dt] = __builtin_amdgcn_mfma_f32_16x16x32_bf16(pf[0], vc[dt], acc[0][dt], 0,0,0);
      acc[1][dt] = __builtin_amdgcn_mfma_f32_16x16x32_bf16(pf[1], vc[dt], acc[1][dt], 0,0,0);
    }
    kc0 = kn0; kc1 = kn1;
    #pragma unroll
    for (int dt=0;dt<4;dt++) vc[dt] = vn[dt];
  }

  #pragma unroll
  for (int qt=0;qt<2;qt++) {
    lsum[qt] += __shfl_xor(lsum[qt], 16, 64);
    lsum[qt] += __shfl_xor(lsum[qt], 32, 64);
  }

  __shared__ float accs[8][32][65];
  __shared__ float dss[16][32];
  if (lane < 16) {
    dss[wave][m]      = lsum[0];
    dss[wave][16 + m] = lsum[1];
  }
  if (wave >= 8) {
    const int wv = wave - 8;
    #pragma unroll
    for (int qt=0;qt<2;qt++)
      #pragma unroll
      for (int dt=0;dt<4;dt++)
        #pragma unroll
        for (int r=0;r<4;r++)
          accs[wv][qt*16 + 4*g + r][dt*16 + m] = acc[qt][dt][r];
  }
  __syncthreads();
  if (wave < 8) {
    #pragma unroll
    for (int qt=0;qt<2;qt++)
      #pragma unroll
      for (int dt=0;dt<4;dt++)
        #pragma unroll
        for (int r=0;r<4;r++)
          accs[wave][qt*16 + 4*g + r][dt*16 + m] += acc[qt][dt][r];
  }
  __syncthreads();
  const float gm = gamma[0];
  #pragma unroll
  for (int s=0;s<2;s++) {
    const int e = threadIdx.x + s * 1024;
    const int r = e >> 6, ln2 = e & 63;
    float denom = 0.f;
    #pragma unroll
    for (int w2=0;w2<16;w2++) denom += dss[w2][r];
    float o = 0.f;
    #pragma unroll
    for (int w2=0;w2<8;w2++) o += accs[w2][r][ln2];
    const int row = q0 + r;
    const float hv = fmaf(gm, o/denom, H3[(size_t)row*64 + ln2]);
    Hatt[(size_t)row*64 + ln2] = hv;
    Hab[(size_t)row*64 + ln2] = bf16of(hv);
  }
}

// ---------------- fused MIL scores via MFMA ----------------
__global__ __launch_bounds__(64) void mil_fused_k(
    const ushort_t* __restrict__ Hab, const ushort_t* __restrict__ Wa1t,
    const float* __restrict__ ba1, const float* __restrict__ Wa2,
    const float* __restrict__ ba2, float* __restrict__ scores)
{
  const int lane = threadIdx.x;
  const int ln = lane & 15, g = lane >> 4;
  const int q0 = blockIdx.x * 16;
  const f32x4 zero4 = {0.f, 0.f, 0.f, 0.f};
  f32x4 acc[4];
  #pragma unroll
  for (int nt = 0; nt < 4; ++nt) acc[nt] = zero4;
  #pragma unroll
  for (int k0 = 0; k0 < 64; k0 += 32) {
    const short8 af = *(const short8*)&Hab[(size_t)(q0 + ln) * 64 + k0 + g * 8];
    #pragma unroll
    for (int nt = 0; nt < 4; ++nt) {
      const short8 bfr = *(const short8*)&Wa1t[(size_t)(nt * 16 + ln) * 64 + k0 + g * 8];
      acc[nt] = __builtin_amdgcn_mfma_f32_16x16x32_bf16(af, bfr, acc[nt], 0, 0, 0);
    }
  }
  #pragma unroll
  for (int r = 0; r < 4; ++r) {
    float s = 0.f;
    #pragma unroll
    for (int nt = 0; nt < 4; ++nt) {
      const int n = nt * 16 + ln;
      s += tanhf(acc[nt][r] + ba1[n]) * Wa2[n];
    }
    s += __shfl_xor(s, 1, 64); s += __shfl_xor(s, 2, 64);
    s += __shfl_xor(s, 4, 64); s += __shfl_xor(s, 8, 64);
    if (ln == 0) scores[q0 + 4 * g + r] = s + ba2[0];
  }
}

// ---------------- pooling stage 1 ----------------
__global__ __launch_bounds__(256) void pool1_k(
    const float* __restrict__ Hm, const float* __restrict__ scores,
    float* __restrict__ pM, float* __restrict__ pS)
{
  const int wave = threadIdx.x >> 6, lane = threadIdx.x & 63;
  const int b = blockIdx.x;
  float macc = 0.f, se = 0.f;
  for (int t=0;t<32;t++) {
    const int i = b*128 + wave*32 + t;
    const float e = __expf(scores[i]);
    se += e;
    macc = fmaf(e, Hm[(size_t)i*64 + lane], macc);
  }
  __shared__ float Ms[4][64];
  __shared__ float Ss[4];
  Ms[wave][lane] = macc;
  if (lane == 0) Ss[wave] = se;
  __syncthreads();
  if (wave == 0) {
    pM[b*64 + lane] = Ms[0][lane]+Ms[1][lane]+Ms[2][lane]+Ms[3][lane];
    if (lane == 0) pS[b] = Ss[0]+Ss[1]+Ss[2]+Ss[3];
  }
}

// ---------------- pooling stage 2 ----------------
__global__ void pool2_k(const float* __restrict__ pM, const float* __restrict__ pS,
                        const float* __restrict__ Wc, const float* __restrict__ bc,
                        float* __restrict__ out)
{
  const int lane = threadIdx.x;
  float s_ = pS[lane];
  s_ += __shfl_xor(s_,1,64);  s_ += __shfl_xor(s_,2,64);
  s_ += __shfl_xor(s_,4,64);  s_ += __shfl_xor(s_,8,64);
  s_ += __shfl_xor(s_,16,64); s_ += __shfl_xor(s_,32,64);
  float m_ = 0.f;
  for (int b=0;b<64;b++) m_ += pM[b*64+lane];
  const float Md = m_ / s_;
  out[1+lane] = Md;
  float yp = Md * Wc[lane];
  yp += __shfl_xor(yp,1,64);  yp += __shfl_xor(yp,2,64);
  yp += __shfl_xor(yp,4,64);  yp += __shfl_xor(yp,8,64);
  yp += __shfl_xor(yp,16,64); yp += __shfl_xor(yp,32,64);
  if (lane == 0) {
    float y = 1.f/(1.f + __expf(-(yp + bc[0])));
    y = fminf(fmaxf(y, 1e-5f), 1.f - 1e-5f);
    out[0] = y;
  }
}

extern "C" void kernel_launch(void* const* d_in, const int* in_sizes, int n_in,
                              void* d_out, int out_size, void* d_ws, size_t ws_size,
                              hipStream_t stream)
{
  const float* x    = (const float*)d_in[0];
  const float* W1   = (const float*)d_in[1];
  const float* b1   = (const float*)d_in[2];
  const float* W2   = (const float*)d_in[3];
  const float* b2   = (const float*)d_in[4];
  const float* W3   = (const float*)d_in[5];
  const float* b3   = (const float*)d_in[6];
  const float* Wq   = (const float*)d_in[7];
  const float* bq   = (const float*)d_in[8];
  const float* Wk   = (const float*)d_in[9];
  const float* bk   = (const float*)d_in[10];
  const float* Wv   = (const float*)d_in[11];
  const float* bv   = (const float*)d_in[12];
  const float* gam  = (const float*)d_in[13];
  const float* Wa1  = (const float*)d_in[14];
  const float* ba1  = (const float*)d_in[15];
  const float* Wa2  = (const float*)d_in[16];
  const float* ba2  = (const float*)d_in[17];
  const float* Wc   = (const float*)d_in[18];
  const float* bc   = (const float*)d_in[19];
  float* out = (float*)d_out;

  char* w = (char*)d_ws;
  float* H3 = (float*)w;        w += (size_t)8192*64*4;
  float* Ha = (float*)w;        w += (size_t)8192*64*4;
  float* sc = (float*)w;        w += 8192*4;
  float* pM = (float*)w;        w += 64*64*4;
  float* pS = (float*)w;        w += 64*4;
  ushort_t* H1b = (ushort_t*)w; w += (size_t)8192*256*2;
  ushort_t* H2b = (ushort_t*)w; w += (size_t)8192*128*2;
  ushort_t* H3b = (ushort_t*)w; w += (size_t)8192*64*2;
  ushort_t* Hab = (ushort_t*)w; w += (size_t)8192*64*2;
  ushort_t* Qb  = (ushort_t*)w; w += (size_t)8192*8*2;
  ushort_t* Kb  = (ushort_t*)w; w += (size_t)8192*8*2;
  ushort_t* VT  = (ushort_t*)w; w += (size_t)64*8192*2;
  ushort_t* W1t = (ushort_t*)w; w += (size_t)256*1024*2;
  ushort_t* W2t = (ushort_t*)w; w += (size_t)128*256*2;
  ushort_t* W3t = (ushort_t*)w; w += (size_t)64*128*2;
  ushort_t* Wa1t= (ushort_t*)w; w += (size_t)64*64*2;
  ushort_t* Wqkv= (ushort_t*)w; w += (size_t)80*64*2;

  transpose_bf16_k<<<dim3(256/32, 1024/32), 256, 0, stream>>>(W1, W1t, 1024, 256);
  transpose_bf16_k<<<dim3(128/32,  256/32), 256, 0, stream>>>(W2, W2t,  256, 128);
  transpose_bf16_k<<<dim3( 64/32,  128/32), 256, 0, stream>>>(W3, W3t,  128,  64);
  transpose_bf16_k<<<dim3( 64/32,   64/32), 256, 0, stream>>>(Wa1, Wa1t,  64,  64);
  prep_qkvw_k<<<1, 256, 0, stream>>>(Wq, Wk, Wv, Wqkv);

  // gemm1: split-K 4x, 16 waves/block, grid 512 -> 32 waves/CU cap
  gemm_splitk<1024,256,256,4,4,true ,0><<<512, 1024, 0, stream>>>(x,   W1t, b1, H1b, nullptr);
  // gemm2: split-K 4x, 8 waves/block
  gemm_splitk< 256, 64,128,2,4,false,0><<<512,  512, 0, stream>>>(H1b, W2t, b2, H2b, nullptr);
  // gemm3: small, plain
  gemm_mfma< 128, 64,1,false,2><<<512, 256, 0, stream>>>(H2b, W3t, b3, H3, H3b);

  qkv_fused_k<<<512, 64, 0, stream>>>(H3b, Wqkv, bq, bk, bv, Qb, Kb, VT);
  attn_mfma_k<<<256, 1024, 0, stream>>>(Qb, Kb, VT, H3, gam, Ha, Hab);
  mil_fused_k<<<512, 64, 0, stream>>>(Hab, Wa1t, ba1, Wa2, ba2, sc);
  pool1_k<<<64, 256, 0, stream>>>(Ha, sc, pM, pS);
  pool2_k<<<1, 64, 0, stream>>>(pM, pS, Wc, bc, out);
}

// Round 9
// 104.149 us; speedup vs baseline: 1.2486x; 1.2486x over previous
//
#include <hip/hip_runtime.h>
#include <math.h>

typedef unsigned short ushort_t;
typedef __attribute__((ext_vector_type(8))) short short8;
typedef __attribute__((ext_vector_type(4))) float f32x4;

__device__ inline unsigned bfpair(float lo, float hi) {
  unsigned r;
  asm("v_cvt_pk_bf16_f32 %0, %1, %2" : "=v"(r) : "v"(lo), "v"(hi));
  return r;
}
__device__ inline ushort_t bf16of(float v) { return (ushort_t)(bfpair(v, v) & 0xffffu); }
__device__ inline void permswap32(unsigned &a, unsigned &b) {
  asm("v_permlane32_swap_b32 %0, %1" : "+v"(a), "+v"(b));
}
__device__ inline void permswap16(unsigned &a, unsigned &b) {
  asm("v_permlane16_swap_b32 %0, %1" : "+v"(a), "+v"(b));
}

// ---------------- transpose + convert: W[K][N] f32 -> Wt[N][K] bf16 ----------------
__global__ __launch_bounds__(256) void transpose_bf16_k(
    const float* __restrict__ W, ushort_t* __restrict__ Wt, int K, int N)
{
  __shared__ float Ls[32][33];
  const int t = threadIdx.x;
  const int n0 = blockIdx.x * 32, k0 = blockIdx.y * 32;
  const int tx = t & 31, tyb = t >> 5;
  #pragma unroll
  for (int s = 0; s < 4; ++s) {
    const int k = tyb + s * 8;
    Ls[k][tx] = W[(size_t)(k0 + k) * N + n0 + tx];
  }
  __syncthreads();
  #pragma unroll
  for (int s = 0; s < 2; ++s) {
    const int idx = t + 256 * s;
    const int n = idx >> 4, kk = (idx & 15) * 2;
    const unsigned pk = bfpair(Ls[kk][n], Ls[kk + 1][n]);
    *(unsigned*)&Wt[(size_t)(n0 + n) * K + k0 + kk] = pk;
  }
}

// ---------------- pack QKV weights: WqkvT[80][64] bf16 ----------------
__global__ __launch_bounds__(256) void prep_qkvw_k(
    const float* __restrict__ Wq, const float* __restrict__ Wk,
    const float* __restrict__ Wv, ushort_t* __restrict__ WqkvT)
{
  for (int e = threadIdx.x; e < 80 * 64; e += 256) {
    const int j = e >> 6, k = e & 63;
    float v;
    if (j < 8)       v = Wq[k * 8 + j];
    else if (j < 16) v = Wk[k * 8 + (j - 8)];
    else             v = Wv[k * 64 + (j - 16)];
    WqkvT[e] = bf16of(v);
  }
}

// ---------------- LDS-staged pipelined bf16 MFMA GEMM + bias + relu ----------------
// BM=32 rows/block, full N covered by WAVES waves (wave = wm*NWN + wn; wm in {0,1},
// wn covers 32 cols with NT=2). Per k-step (32 k): block bulk-stages A(32x32) and
// B(Nx32) into double-buffered padded LDS; each thread prefetches its next-tile
// 16B chunk a full k-step early (one vmcnt wait per iter). Requires NTH == N*4.
// HW-verified frag maps: A lane(g,ln): A[m=ln][k=8g+i]; B: Wt[n][k=8g+i];
// D lane(g,ln) reg r: (row=4g+r, col=ln).
template<int K, int N, int WAVES, bool A_FP32, int OMODE>
__global__ __launch_bounds__(WAVES * 64) void gemm_staged(
    const void* __restrict__ Ap, const ushort_t* __restrict__ Wt,
    const float* __restrict__ bias, void* __restrict__ C0, void* __restrict__ C1)
{
  constexpr int BM = 32;
  constexpr int NWN = N / 32;
  constexpr int NK = K / 32;
  constexpr int A_CH = BM * 4;          // 16B-chunks for A tile
  constexpr int B_CH = N * 4;           // 16B-chunks for B tile
  static_assert(WAVES * 64 == B_CH, "threads must equal B chunk count");
  static_assert(A_CH <= WAVES * 64, "");

  const int tid = threadIdx.x;
  const int wave = tid >> 6, lane = tid & 63;
  const int ln = lane & 15, g = lane >> 4;
  const int wm = wave / NWN, wn = wave % NWN;
  const int bm0 = blockIdx.x * BM;

  __shared__ ushort_t Als[2][BM][40];
  __shared__ ushort_t Bls[2][N][40];

  const float* Af = (const float*)Ap;
  const ushort_t* Ab = (const ushort_t*)Ap;

  const bool hasA = (tid < A_CH);
  const int arow = tid >> 2, akq = tid & 3;
  const int bc = hasA ? (B_CH - A_CH + tid) : (tid - A_CH);
  const int brow = bc >> 2, bkq = bc & 3;

  float4 rf0, rf1;
  short8 ra, rb;

  auto LOADK = [&](int ks) {
    const int k0 = ks * 32;
    if (hasA) {
      if (A_FP32) {
        const float* src = &Af[(size_t)(bm0 + arow) * K + k0 + akq * 8];
        rf0 = *(const float4*)src;
        rf1 = *(const float4*)(src + 4);
      } else {
        ra = *(const short8*)&Ab[(size_t)(bm0 + arow) * K + k0 + akq * 8];
      }
    }
    rb = *(const short8*)&Wt[(size_t)brow * K + k0 + bkq * 8];
  };
  auto WRITEK = [&](int cur) {
    if (hasA) {
      short8 wa;
      if (A_FP32) {
        union { unsigned u[4]; short8 s8; } cv;
        cv.u[0] = bfpair(rf0.x, rf0.y);
        cv.u[1] = bfpair(rf0.z, rf0.w);
        cv.u[2] = bfpair(rf1.x, rf1.y);
        cv.u[3] = bfpair(rf1.z, rf1.w);
        wa = cv.s8;
      } else {
        wa = ra;
      }
      *(short8*)&Als[cur][arow][akq * 8] = wa;
    }
    *(short8*)&Bls[cur][brow][bkq * 8] = rb;
  };

  f32x4 acc0 = {0.f, 0.f, 0.f, 0.f};
  f32x4 acc1 = {0.f, 0.f, 0.f, 0.f};

  LOADK(0);
  int cur = 0;
  for (int ks = 0; ks < NK; ++ks) {
    WRITEK(cur);
    __syncthreads();
    if (ks + 1 < NK) LOADK(ks + 1);
    const short8 af = *(const short8*)&Als[cur][wm * 16 + ln][g * 8];
    const short8 b0 = *(const short8*)&Bls[cur][wn * 32 + ln][g * 8];
    const short8 b1 = *(const short8*)&Bls[cur][wn * 32 + 16 + ln][g * 8];
    acc0 = __builtin_amdgcn_mfma_f32_16x16x32_bf16(af, b0, acc0, 0, 0, 0);
    acc1 = __builtin_amdgcn_mfma_f32_16x16x32_bf16(af, b1, acc1, 0, 0, 0);
    cur ^= 1;
    // no barrier needed here: double buffer + top-of-loop barrier fences reuse
  }

  #pragma unroll
  for (int nt = 0; nt < 2; ++nt) {
    const f32x4 a = nt ? acc1 : acc0;
    #pragma unroll
    for (int r = 0; r < 4; ++r) {
      const int m = bm0 + wm * 16 + 4 * g + r;
      const int n = wn * 32 + nt * 16 + ln;
      float v = a[r] + bias[n];
      v = fmaxf(v, 0.f);
      if (OMODE == 0) {
        ((ushort_t*)C0)[(size_t)m * N + n] = bf16of(v);
      } else if (OMODE == 1) {
        ((float*)C0)[(size_t)m * N + n] = v;
      } else {
        ((float*)C0)[(size_t)m * N + n] = v;
        ((ushort_t*)C1)[(size_t)m * N + n] = bf16of(v);
      }
    }
  }
}

// ---------------- plain bf16 MFMA GEMM (small gemm3) ----------------
template<int K, int N, int NT, bool A_FP32, int OMODE>
__global__ __launch_bounds__(256) void gemm_mfma(
    const void* __restrict__ Ap, const ushort_t* __restrict__ Wt,
    const float* __restrict__ bias, void* __restrict__ C0, void* __restrict__ C1)
{
  const int wave = threadIdx.x >> 6, lane = threadIdx.x & 63;
  const int ln = lane & 15, g = lane >> 4;
  const int bm0 = blockIdx.x * 16;
  const int n0 = wave * (NT * 16);
  const f32x4 zero4 = {0.f, 0.f, 0.f, 0.f};
  f32x4 acc[NT];
  #pragma unroll
  for (int nt = 0; nt < NT; ++nt) acc[nt] = zero4;
  const float* Af = (const float*)Ap;
  const ushort_t* Ab = (const ushort_t*)Ap;
  #pragma unroll 2
  for (int k0 = 0; k0 < K; k0 += 32) {
    short8 af;
    const size_t abase = (size_t)(bm0 + ln) * K + k0 + g * 8;
    if (A_FP32) {
      const float4 f0 = *(const float4*)&Af[abase];
      const float4 f1 = *(const float4*)&Af[abase + 4];
      union { unsigned u[4]; short8 s8; } cv;
      cv.u[0] = bfpair(f0.x, f0.y);
      cv.u[1] = bfpair(f0.z, f0.w);
      cv.u[2] = bfpair(f1.x, f1.y);
      cv.u[3] = bfpair(f1.z, f1.w);
      af = cv.s8;
    } else {
      af = *(const short8*)&Ab[abase];
    }
    short8 bfr[NT];
    #pragma unroll
    for (int nt = 0; nt < NT; ++nt)
      bfr[nt] = *(const short8*)&Wt[(size_t)(n0 + nt * 16 + ln) * K + k0 + g * 8];
    #pragma unroll
    for (int nt = 0; nt < NT; ++nt)
      acc[nt] = __builtin_amdgcn_mfma_f32_16x16x32_bf16(af, bfr[nt], acc[nt], 0, 0, 0);
  }
  #pragma unroll
  for (int nt = 0; nt < NT; ++nt)
    #pragma unroll
    for (int r = 0; r < 4; ++r) {
      const int m = bm0 + 4 * g + r;
      const int n = n0 + nt * 16 + ln;
      float v = acc[nt][r] + bias[n];
      v = fmaxf(v, 0.f);
      if (OMODE == 0) {
        ((ushort_t*)C0)[(size_t)m * N + n] = bf16of(v);
      } else if (OMODE == 1) {
        ((float*)C0)[(size_t)m * N + n] = v;
      } else {
        ((float*)C0)[(size_t)m * N + n] = v;
        ((ushort_t*)C1)[(size_t)m * N + n] = bf16of(v);
      }
    }
}

// ---------------- fused QKV via MFMA ----------------
__global__ __launch_bounds__(64) void qkv_fused_k(
    const ushort_t* __restrict__ H3b, const ushort_t* __restrict__ WqkvT,
    const float* __restrict__ bq, const float* __restrict__ bk, const float* __restrict__ bv,
    ushort_t* __restrict__ Qb, ushort_t* __restrict__ Kb, ushort_t* __restrict__ VT)
{
  const int lane = threadIdx.x;
  const int ln = lane & 15, g = lane >> 4;
  const int q0 = blockIdx.x * 16;
  const f32x4 zero4 = {0.f, 0.f, 0.f, 0.f};
  f32x4 acc[5];
  #pragma unroll
  for (int nt = 0; nt < 5; ++nt) acc[nt] = zero4;
  #pragma unroll
  for (int k0 = 0; k0 < 64; k0 += 32) {
    const short8 af = *(const short8*)&H3b[(size_t)(q0 + ln) * 64 + k0 + g * 8];
    #pragma unroll
    for (int nt = 0; nt < 5; ++nt) {
      const short8 bfr = *(const short8*)&WqkvT[(size_t)(nt * 16 + ln) * 64 + k0 + g * 8];
      acc[nt] = __builtin_amdgcn_mfma_f32_16x16x32_bf16(af, bfr, acc[nt], 0, 0, 0);
    }
  }
  {
    const float b0 = (ln < 8) ? bq[ln] : bk[ln - 8];
    #pragma unroll
    for (int r = 0; r < 4; ++r) {
      const int m = q0 + 4 * g + r;
      const float v = acc[0][r] + b0;
      if (ln < 8) Qb[(size_t)m * 8 + ln] = bf16of(v);
      else        Kb[(size_t)m * 8 + (ln - 8)] = bf16of(v);
    }
  }
  #pragma unroll
  for (int nt = 1; nt < 5; ++nt) {
    const int d = nt * 16 + ln - 16;
    const float b0 = bv[d];
    const float v0 = acc[nt][0] + b0, v1 = acc[nt][1] + b0;
    const float v2 = acc[nt][2] + b0, v3 = acc[nt][3] + b0;
    uint2 o; o.x = bfpair(v0, v1); o.y = bfpair(v2, v3);
    *(uint2*)&VT[(size_t)d * 8192 + q0 + 4 * g] = o;
  }
}

// ---------------- MFMA flash attention + residual (R7/8-verified) ----------------
__global__ __launch_bounds__(1024) void attn_mfma_k(
    const ushort_t* __restrict__ Qb, const ushort_t* __restrict__ Kb,
    const ushort_t* __restrict__ VT, const float* __restrict__ H3,
    const float* __restrict__ gamma, float* __restrict__ Hatt,
    ushort_t* __restrict__ Hab)
{
  const int wave = threadIdx.x >> 6, lane = threadIdx.x & 63;
  const int q0 = blockIdx.x * 32;
  const int m = lane & 15, g = lane >> 4;
  const f32x4 zero4 = {0.f,0.f,0.f,0.f};

  short8 qf[2] = {{0,0,0,0,0,0,0,0},{0,0,0,0,0,0,0,0}};
  if (lane < 16) {
    qf[0] = *(const short8*)&Qb[(size_t)(q0 + m) * 8];
    qf[1] = *(const short8*)&Qb[(size_t)(q0 + 16 + m) * 8];
  }

  f32x4 acc[2][4];
  #pragma unroll
  for (int qt=0;qt<2;qt++)
    #pragma unroll
    for (int dt=0;dt<4;dt++) acc[qt][dt] = zero4;
  float lsum[2] = {0.f, 0.f};

  const int j0w = wave << 9;   // 512 j per wave
  short8 kc0 = {0,0,0,0,0,0,0,0}, kc1 = {0,0,0,0,0,0,0,0};
  short8 vc[4];
  if (lane < 16) {
    kc0 = *(const short8*)&Kb[(size_t)(j0w + m) * 8];
    kc1 = *(const short8*)&Kb[(size_t)(j0w + 16 + m) * 8];
  }
  {
    const size_t vbase = (size_t)j0w + (size_t)(g << 3);
    #pragma unroll
    for (int dt=0;dt<4;dt++)
      vc[dt] = *(const short8*)&VT[(size_t)(dt*16 + m) * 8192 + vbase];
  }

  #pragma unroll 1
  for (int jc = 0; jc < 512; jc += 32) {
    const int jb = j0w + jc;
    const int jn = (jc + 32 < 512) ? (jb + 32) : j0w;
    short8 kn0 = {0,0,0,0,0,0,0,0}, kn1 = {0,0,0,0,0,0,0,0};
    short8 vn[4];
    if (lane < 16) {
      kn0 = *(const short8*)&Kb[(size_t)(jn + m) * 8];
      kn1 = *(const short8*)&Kb[(size_t)(jn + 16 + m) * 8];
    }
    const size_t vnbase = (size_t)jn + (size_t)(g << 3);
    #pragma unroll
    for (int dt=0;dt<4;dt++)
      vn[dt] = *(const short8*)&VT[(size_t)(dt*16 + m) * 8192 + vnbase];

    short8 pf[2];
    #pragma unroll
    for (int qt=0;qt<2;qt++) {
      const f32x4 s0 = __builtin_amdgcn_mfma_f32_16x16x32_bf16(kc0, qf[qt], zero4, 0,0,0);
      const f32x4 s1 = __builtin_amdgcn_mfma_f32_16x16x32_bf16(kc1, qf[qt], zero4, 0,0,0);
      const float e00 = __expf(s0[0]), e01 = __expf(s0[1]), e02 = __expf(s0[2]), e03 = __expf(s0[3]);
      const float e10 = __expf(s1[0]), e11 = __expf(s1[1]), e12 = __expf(s1[2]), e13 = __expf(s1[3]);
      lsum[qt] += ((e00+e01)+(e02+e03)) + ((e10+e11)+(e12+e13));
      unsigned X01 = bfpair(e00,e01), X23 = bfpair(e02,e03);
      unsigned Y01 = bfpair(e10,e11), Y23 = bfpair(e12,e13);
      permswap32(X01, Y01); permswap16(X01, Y01);
      permswap32(X23, Y23); permswap16(X23, Y23);
      union { unsigned u[4]; short8 s; } pfu;
      pfu.u[0] = X01;
      pfu.u[1] = X23;
      pfu.u[2] = Y01;
      pfu.u[3] = Y23;
      pf[qt] = pfu.s;
    }
    #pragma unroll
    for (int dt=0;dt<4;dt++) {
      acc[0][dt] = __builtin_amdgcn_mfma_f32_16x16x32_bf16(pf[0], vc[dt], acc[0][dt], 0,0,0);
      acc[1][dt] = __builtin_amdgcn_mfma_f32_16x16x32_bf16(pf[1], vc[dt], acc[1][dt], 0,0,0);
    }
    kc0 = kn0; kc1 = kn1;
    #pragma unroll
    for (int dt=0;dt<4;dt++) vc[dt] = vn[dt];
  }

  #pragma unroll
  for (int qt=0;qt<2;qt++) {
    lsum[qt] += __shfl_xor(lsum[qt], 16, 64);
    lsum[qt] += __shfl_xor(lsum[qt], 32, 64);
  }

  __shared__ float accs[8][32][65];
  __shared__ float dss[16][32];
  if (lane < 16) {
    dss[wave][m]      = lsum[0];
    dss[wave][16 + m] = lsum[1];
  }
  if (wave >= 8) {
    const int wv = wave - 8;
    #pragma unroll
    for (int qt=0;qt<2;qt++)
      #pragma unroll
      for (int dt=0;dt<4;dt++)
        #pragma unroll
        for (int r=0;r<4;r++)
          accs[wv][qt*16 + 4*g + r][dt*16 + m] = acc[qt][dt][r];
  }
  __syncthreads();
  if (wave < 8) {
    #pragma unroll
    for (int qt=0;qt<2;qt++)
      #pragma unroll
      for (int dt=0;dt<4;dt++)
        #pragma unroll
        for (int r=0;r<4;r++)
          accs[wave][qt*16 + 4*g + r][dt*16 + m] += acc[qt][dt][r];
  }
  __syncthreads();
  const float gm = gamma[0];
  #pragma unroll
  for (int s=0;s<2;s++) {
    const int e = threadIdx.x + s * 1024;
    const int r = e >> 6, ln2 = e & 63;
    float denom = 0.f;
    #pragma unroll
    for (int w2=0;w2<16;w2++) denom += dss[w2][r];
    float o = 0.f;
    #pragma unroll
    for (int w2=0;w2<8;w2++) o += accs[w2][r][ln2];
    const int row = q0 + r;
    const float hv = fmaf(gm, o/denom, H3[(size_t)row*64 + ln2]);
    Hatt[(size_t)row*64 + ln2] = hv;
    Hab[(size_t)row*64 + ln2] = bf16of(hv);
  }
}

// ---------------- fused MIL scores via MFMA ----------------
__global__ __launch_bounds__(64) void mil_fused_k(
    const ushort_t* __restrict__ Hab, const ushort_t* __restrict__ Wa1t,
    const float* __restrict__ ba1, const float* __restrict__ Wa2,
    const float* __restrict__ ba2, float* __restrict__ scores)
{
  const int lane = threadIdx.x;
  const int ln = lane & 15, g = lane >> 4;
  const int q0 = blockIdx.x * 16;
  const f32x4 zero4 = {0.f, 0.f, 0.f, 0.f};
  f32x4 acc[4];
  #pragma unroll
  for (int nt = 0; nt < 4; ++nt) acc[nt] = zero4;
  #pragma unroll
  for (int k0 = 0; k0 < 64; k0 += 32) {
    const short8 af = *(const short8*)&Hab[(size_t)(q0 + ln) * 64 + k0 + g * 8];
    #pragma unroll
    for (int nt = 0; nt < 4; ++nt) {
      const short8 bfr = *(const short8*)&Wa1t[(size_t)(nt * 16 + ln) * 64 + k0 + g * 8];
      acc[nt] = __builtin_amdgcn_mfma_f32_16x16x32_bf16(af, bfr, acc[nt], 0, 0, 0);
    }
  }
  #pragma unroll
  for (int r = 0; r < 4; ++r) {
    float s = 0.f;
    #pragma unroll
    for (int nt = 0; nt < 4; ++nt) {
      const int n = nt * 16 + ln;
      s += tanhf(acc[nt][r] + ba1[n]) * Wa2[n];
    }
    s += __shfl_xor(s, 1, 64); s += __shfl_xor(s, 2, 64);
    s += __shfl_xor(s, 4, 64); s += __shfl_xor(s, 8, 64);
    if (ln == 0) scores[q0 + 4 * g + r] = s + ba2[0];
  }
}

// ---------------- pooling stage 1 ----------------
__global__ __launch_bounds__(256) void pool1_k(
    const float* __restrict__ Hm, const float* __restrict__ scores,
    float* __restrict__ pM, float* __restrict__ pS)
{
  const int wave = threadIdx.x >> 6, lane = threadIdx.x & 63;
  const int b = blockIdx.x;
  float macc = 0.f, se = 0.f;
  for (int t=0;t<32;t++) {
    const int i = b*128 + wave*32 + t;
    const float e = __expf(scores[i]);
    se += e;
    macc = fmaf(e, Hm[(size_t)i*64 + lane], macc);
  }
  __shared__ float Ms[4][64];
  __shared__ float Ss[4];
  Ms[wave][lane] = macc;
  if (lane == 0) Ss[wave] = se;
  __syncthreads();
  if (wave == 0) {
    pM[b*64 + lane] = Ms[0][lane]+Ms[1][lane]+Ms[2][lane]+Ms[3][lane];
    if (lane == 0) pS[b] = Ss[0]+Ss[1]+Ss[2]+Ss[3];
  }
}

// ---------------- pooling stage 2 ----------------
__global__ void pool2_k(const float* __restrict__ pM, const float* __restrict__ pS,
                        const float* __restrict__ Wc, const float* __restrict__ bc,
                        float* __restrict__ out)
{
  const int lane = threadIdx.x;
  float s_ = pS[lane];
  s_ += __shfl_xor(s_,1,64);  s_ += __shfl_xor(s_,2,64);
  s_ += __shfl_xor(s_,4,64);  s_ += __shfl_xor(s_,8,64);
  s_ += __shfl_xor(s_,16,64); s_ += __shfl_xor(s_,32,64);
  float m_ = 0.f;
  for (int b=0;b<64;b++) m_ += pM[b*64+lane];
  const float Md = m_ / s_;
  out[1+lane] = Md;
  float yp = Md * Wc[lane];
  yp += __shfl_xor(yp,1,64);  yp += __shfl_xor(yp,2,64);
  yp += __shfl_xor(yp,4,64);  yp += __shfl_xor(yp,8,64);
  yp += __shfl_xor(yp,16,64); yp += __shfl_xor(yp,32,64);
  if (lane == 0) {
    float y = 1.f/(1.f + __expf(-(yp + bc[0])));
    y = fminf(fmaxf(y, 1e-5f), 1.f - 1e-5f);
    out[0] = y;
  }
}

extern "C" void kernel_launch(void* const* d_in, const int* in_sizes, int n_in,
                              void* d_out, int out_size, void* d_ws, size_t ws_size,
                              hipStream_t stream)
{
  const float* x    = (const float*)d_in[0];
  const float* W1   = (const float*)d_in[1];
  const float* b1   = (const float*)d_in[2];
  const float* W2   = (const float*)d_in[3];
  const float* b2   = (const float*)d_in[4];
  const float* W3   = (const float*)d_in[5];
  const float* b3   = (const float*)d_in[6];
  const float* Wq   = (const float*)d_in[7];
  const float* bq   = (const float*)d_in[8];
  const float* Wk   = (const float*)d_in[9];
  const float* bk   = (const float*)d_in[10];
  const float* Wv   = (const float*)d_in[11];
  const float* bv   = (const float*)d_in[12];
  const float* gam  = (const float*)d_in[13];
  const float* Wa1  = (const float*)d_in[14];
  const float* ba1  = (const float*)d_in[15];
  const float* Wa2  = (const float*)d_in[16];
  const float* ba2  = (const float*)d_in[17];
  const float* Wc   = (const float*)d_in[18];
  const float* bc   = (const float*)d_in[19];
  float* out = (float*)d_out;

  char* w = (char*)d_ws;
  float* H3 = (float*)w;        w += (size_t)8192*64*4;
  float* Ha = (float*)w;        w += (size_t)8192*64*4;
  float* sc = (float*)w;        w += 8192*4;
  float* pM = (float*)w;        w += 64*64*4;
  float* pS = (float*)w;        w += 64*4;
  ushort_t* H1b = (ushort_t*)w; w += (size_t)8192*256*2;
  ushort_t* H2b = (ushort_t*)w; w += (size_t)8192*128*2;
  ushort_t* H3b = (ushort_t*)w; w += (size_t)8192*64*2;
  ushort_t* Hab = (ushort_t*)w; w += (size_t)8192*64*2;
  ushort_t* Qb  = (ushort_t*)w; w += (size_t)8192*8*2;
  ushort_t* Kb  = (ushort_t*)w; w += (size_t)8192*8*2;
  ushort_t* VT  = (ushort_t*)w; w += (size_t)64*8192*2;
  ushort_t* W1t = (ushort_t*)w; w += (size_t)256*1024*2;
  ushort_t* W2t = (ushort_t*)w; w += (size_t)128*256*2;
  ushort_t* W3t = (ushort_t*)w; w += (size_t)64*128*2;
  ushort_t* Wa1t= (ushort_t*)w; w += (size_t)64*64*2;
  ushort_t* Wqkv= (ushort_t*)w; w += (size_t)80*64*2;

  transpose_bf16_k<<<dim3(256/32, 1024/32), 256, 0, stream>>>(W1, W1t, 1024, 256);
  transpose_bf16_k<<<dim3(128/32,  256/32), 256, 0, stream>>>(W2, W2t,  256, 128);
  transpose_bf16_k<<<dim3( 64/32,  128/32), 256, 0, stream>>>(W3, W3t,  128,  64);
  transpose_bf16_k<<<dim3( 64/32,   64/32), 256, 0, stream>>>(Wa1, Wa1t,  64,  64);
  prep_qkvw_k<<<1, 256, 0, stream>>>(Wq, Wk, Wv, Wqkv);

  // gemm1: LDS-staged pipeline, BM=32, 16 waves, grid 256
  gemm_staged<1024,256,16,true ,0><<<256, 1024, 0, stream>>>(x,   W1t, b1, H1b, nullptr);
  // gemm2: same structure, 8 waves
  gemm_staged< 256,128, 8,false,0><<<256,  512, 0, stream>>>(H1b, W2t, b2, H2b, nullptr);
  // gemm3: small, plain
  gemm_mfma< 128, 64,1,false,2><<<512, 256, 0, stream>>>(H2b, W3t, b3, H3, H3b);

  qkv_fused_k<<<512, 64, 0, stream>>>(H3b, Wqkv, bq, bk, bv, Qb, Kb, VT);
  attn_mfma_k<<<256, 1024, 0, stream>>>(Qb, Kb, VT, H3, gam, Ha, Hab);
  mil_fused_k<<<512, 64, 0, stream>>>(Hab, Wa1t, ba1, Wa2, ba2, sc);
  pool1_k<<<64, 256, 0, stream>>>(Ha, sc, pM, pS);
  pool2_k<<<1, 64, 0, stream>>>(pM, pS, Wc, bc, out);
}

// Round 10
// 94.763 us; speedup vs baseline: 1.3723x; 1.0991x over previous
//
#include <hip/hip_runtime.h>
#include <math.h>

typedef unsigned short ushort_t;
typedef __attribute__((ext_vector_type(8))) short short8;
typedef __attribute__((ext_vector_type(4))) float f32x4;

__device__ inline unsigned bfpair(float lo, float hi) {
  unsigned r;
  asm("v_cvt_pk_bf16_f32 %0, %1, %2" : "=v"(r) : "v"(lo), "v"(hi));
  return r;
}
__device__ inline ushort_t bf16of(float v) { return (ushort_t)(bfpair(v, v) & 0xffffu); }
__device__ inline void permswap32(unsigned &a, unsigned &b) {
  asm("v_permlane32_swap_b32 %0, %1" : "+v"(a), "+v"(b));
}
__device__ inline void permswap16(unsigned &a, unsigned &b) {
  asm("v_permlane16_swap_b32 %0, %1" : "+v"(a), "+v"(b));
}

// ---------------- transpose + convert: W[K][N] f32 -> Wt[N][K] bf16 ----------------
__global__ __launch_bounds__(256) void transpose_bf16_k(
    const float* __restrict__ W, ushort_t* __restrict__ Wt, int K, int N)
{
  __shared__ float Ls[32][33];
  const int t = threadIdx.x;
  const int n0 = blockIdx.x * 32, k0 = blockIdx.y * 32;
  const int tx = t & 31, tyb = t >> 5;
  #pragma unroll
  for (int s = 0; s < 4; ++s) {
    const int k = tyb + s * 8;
    Ls[k][tx] = W[(size_t)(k0 + k) * N + n0 + tx];
  }
  __syncthreads();
  #pragma unroll
  for (int s = 0; s < 2; ++s) {
    const int idx = t + 256 * s;
    const int n = idx >> 4, kk = (idx & 15) * 2;
    const unsigned pk = bfpair(Ls[kk][n], Ls[kk + 1][n]);
    *(unsigned*)&Wt[(size_t)(n0 + n) * K + k0 + kk] = pk;
  }
}

// ---------------- pack QKV weights: WqkvT[80][64] bf16 ----------------
__global__ __launch_bounds__(256) void prep_qkvw_k(
    const float* __restrict__ Wq, const float* __restrict__ Wk,
    const float* __restrict__ Wv, ushort_t* __restrict__ WqkvT)
{
  for (int e = threadIdx.x; e < 80 * 64; e += 256) {
    const int j = e >> 6, k = e & 63;
    float v;
    if (j < 8)       v = Wq[k * 8 + j];
    else if (j < 16) v = Wk[k * 8 + (j - 8)];
    else             v = Wv[k * 64 + (j - 16)];
    WqkvT[e] = bf16of(v);
  }
}

// ---------------- LDS-staged pipelined bf16 MFMA GEMM + bias + relu (R9-verified) ----------------
template<int K, int N, int WAVES, bool A_FP32, int OMODE>
__global__ __launch_bounds__(WAVES * 64) void gemm_staged(
    const void* __restrict__ Ap, const ushort_t* __restrict__ Wt,
    const float* __restrict__ bias, void* __restrict__ C0, void* __restrict__ C1)
{
  constexpr int BM = 32;
  constexpr int NWN = N / 32;
  constexpr int NK = K / 32;
  constexpr int A_CH = BM * 4;
  constexpr int B_CH = N * 4;
  static_assert(WAVES * 64 == B_CH, "threads must equal B chunk count");
  static_assert(A_CH <= WAVES * 64, "");

  const int tid = threadIdx.x;
  const int wave = tid >> 6, lane = tid & 63;
  const int ln = lane & 15, g = lane >> 4;
  const int wm = wave / NWN, wn = wave % NWN;
  const int bm0 = blockIdx.x * BM;

  __shared__ ushort_t Als[2][BM][40];
  __shared__ ushort_t Bls[2][N][40];

  const float* Af = (const float*)Ap;
  const ushort_t* Ab = (const ushort_t*)Ap;

  const bool hasA = (tid < A_CH);
  const int arow = tid >> 2, akq = tid & 3;
  const int bc = hasA ? (B_CH - A_CH + tid) : (tid - A_CH);
  const int brow = bc >> 2, bkq = bc & 3;

  float4 rf0, rf1;
  short8 ra, rb;

  auto LOADK = [&](int ks) {
    const int k0 = ks * 32;
    if (hasA) {
      if (A_FP32) {
        const float* src = &Af[(size_t)(bm0 + arow) * K + k0 + akq * 8];
        rf0 = *(const float4*)src;
        rf1 = *(const float4*)(src + 4);
      } else {
        ra = *(const short8*)&Ab[(size_t)(bm0 + arow) * K + k0 + akq * 8];
      }
    }
    rb = *(const short8*)&Wt[(size_t)brow * K + k0 + bkq * 8];
  };
  auto WRITEK = [&](int cur) {
    if (hasA) {
      short8 wa;
      if (A_FP32) {
        union { unsigned u[4]; short8 s8; } cv;
        cv.u[0] = bfpair(rf0.x, rf0.y);
        cv.u[1] = bfpair(rf0.z, rf0.w);
        cv.u[2] = bfpair(rf1.x, rf1.y);
        cv.u[3] = bfpair(rf1.z, rf1.w);
        wa = cv.s8;
      } else {
        wa = ra;
      }
      *(short8*)&Als[cur][arow][akq * 8] = wa;
    }
    *(short8*)&Bls[cur][brow][bkq * 8] = rb;
  };

  f32x4 acc0 = {0.f, 0.f, 0.f, 0.f};
  f32x4 acc1 = {0.f, 0.f, 0.f, 0.f};

  LOADK(0);
  int cur = 0;
  for (int ks = 0; ks < NK; ++ks) {
    WRITEK(cur);
    __syncthreads();
    if (ks + 1 < NK) LOADK(ks + 1);
    const short8 af = *(const short8*)&Als[cur][wm * 16 + ln][g * 8];
    const short8 b0 = *(const short8*)&Bls[cur][wn * 32 + ln][g * 8];
    const short8 b1 = *(const short8*)&Bls[cur][wn * 32 + 16 + ln][g * 8];
    acc0 = __builtin_amdgcn_mfma_f32_16x16x32_bf16(af, b0, acc0, 0, 0, 0);
    acc1 = __builtin_amdgcn_mfma_f32_16x16x32_bf16(af, b1, acc1, 0, 0, 0);
    cur ^= 1;
  }

  #pragma unroll
  for (int nt = 0; nt < 2; ++nt) {
    const f32x4 a = nt ? acc1 : acc0;
    #pragma unroll
    for (int r = 0; r < 4; ++r) {
      const int m = bm0 + wm * 16 + 4 * g + r;
      const int n = wn * 32 + nt * 16 + ln;
      float v = a[r] + bias[n];
      v = fmaxf(v, 0.f);
      if (OMODE == 0) {
        ((ushort_t*)C0)[(size_t)m * N + n] = bf16of(v);
      } else if (OMODE == 1) {
        ((float*)C0)[(size_t)m * N + n] = v;
      } else {
        ((float*)C0)[(size_t)m * N + n] = v;
        ((ushort_t*)C1)[(size_t)m * N + n] = bf16of(v);
      }
    }
  }
}

// ---------------- plain bf16 MFMA GEMM (small gemm3) ----------------
template<int K, int N, int NT, bool A_FP32, int OMODE>
__global__ __launch_bounds__(256) void gemm_mfma(
    const void* __restrict__ Ap, const ushort_t* __restrict__ Wt,
    const float* __restrict__ bias, void* __restrict__ C0, void* __restrict__ C1)
{
  const int wave = threadIdx.x >> 6, lane = threadIdx.x & 63;
  const int ln = lane & 15, g = lane >> 4;
  const int bm0 = blockIdx.x * 16;
  const int n0 = wave * (NT * 16);
  const f32x4 zero4 = {0.f, 0.f, 0.f, 0.f};
  f32x4 acc[NT];
  #pragma unroll
  for (int nt = 0; nt < NT; ++nt) acc[nt] = zero4;
  const float* Af = (const float*)Ap;
  const ushort_t* Ab = (const ushort_t*)Ap;
  #pragma unroll 2
  for (int k0 = 0; k0 < K; k0 += 32) {
    short8 af;
    const size_t abase = (size_t)(bm0 + ln) * K + k0 + g * 8;
    if (A_FP32) {
      const float4 f0 = *(const float4*)&Af[abase];
      const float4 f1 = *(const float4*)&Af[abase + 4];
      union { unsigned u[4]; short8 s8; } cv;
      cv.u[0] = bfpair(f0.x, f0.y);
      cv.u[1] = bfpair(f0.z, f0.w);
      cv.u[2] = bfpair(f1.x, f1.y);
      cv.u[3] = bfpair(f1.z, f1.w);
      af = cv.s8;
    } else {
      af = *(const short8*)&Ab[abase];
    }
    short8 bfr[NT];
    #pragma unroll
    for (int nt = 0; nt < NT; ++nt)
      bfr[nt] = *(const short8*)&Wt[(size_t)(n0 + nt * 16 + ln) * K + k0 + g * 8];
    #pragma unroll
    for (int nt = 0; nt < NT; ++nt)
      acc[nt] = __builtin_amdgcn_mfma_f32_16x16x32_bf16(af, bfr[nt], acc[nt], 0, 0, 0);
  }
  #pragma unroll
  for (int nt = 0; nt < NT; ++nt)
    #pragma unroll
    for (int r = 0; r < 4; ++r) {
      const int m = bm0 + 4 * g + r;
      const int n = n0 + nt * 16 + ln;
      float v = acc[nt][r] + bias[n];
      v = fmaxf(v, 0.f);
      if (OMODE == 0) {
        ((ushort_t*)C0)[(size_t)m * N + n] = bf16of(v);
      } else if (OMODE == 1) {
        ((float*)C0)[(size_t)m * N + n] = v;
      } else {
        ((float*)C0)[(size_t)m * N + n] = v;
        ((ushort_t*)C1)[(size_t)m * N + n] = bf16of(v);
      }
    }
}

// ---------------- fused QKV via MFMA ----------------
__global__ __launch_bounds__(64) void qkv_fused_k(
    const ushort_t* __restrict__ H3b, const ushort_t* __restrict__ WqkvT,
    const float* __restrict__ bq, const float* __restrict__ bk, const float* __restrict__ bv,
    ushort_t* __restrict__ Qb, ushort_t* __restrict__ Kb, ushort_t* __restrict__ VT)
{
  const int lane = threadIdx.x;
  const int ln = lane & 15, g = lane >> 4;
  const int q0 = blockIdx.x * 16;
  const f32x4 zero4 = {0.f, 0.f, 0.f, 0.f};
  f32x4 acc[5];
  #pragma unroll
  for (int nt = 0; nt < 5; ++nt) acc[nt] = zero4;
  #pragma unroll
  for (int k0 = 0; k0 < 64; k0 += 32) {
    const short8 af = *(const short8*)&H3b[(size_t)(q0 + ln) * 64 + k0 + g * 8];
    #pragma unroll
    for (int nt = 0; nt < 5; ++nt) {
      const short8 bfr = *(const short8*)&WqkvT[(size_t)(nt * 16 + ln) * 64 + k0 + g * 8];
      acc[nt] = __builtin_amdgcn_mfma_f32_16x16x32_bf16(af, bfr, acc[nt], 0, 0, 0);
    }
  }
  {
    const float b0 = (ln < 8) ? bq[ln] : bk[ln - 8];
    #pragma unroll
    for (int r = 0; r < 4; ++r) {
      const int m = q0 + 4 * g + r;
      const float v = acc[0][r] + b0;
      if (ln < 8) Qb[(size_t)m * 8 + ln] = bf16of(v);
      else        Kb[(size_t)m * 8 + (ln - 8)] = bf16of(v);
    }
  }
  #pragma unroll
  for (int nt = 1; nt < 5; ++nt) {
    const int d = nt * 16 + ln - 16;
    const float b0 = bv[d];
    const float v0 = acc[nt][0] + b0, v1 = acc[nt][1] + b0;
    const float v2 = acc[nt][2] + b0, v3 = acc[nt][3] + b0;
    uint2 o; o.x = bfpair(v0, v1); o.y = bfpair(v2, v3);
    *(uint2*)&VT[(size_t)d * 8192 + q0 + 4 * g] = o;
  }
}

// ---------------- attention pass 1: LDS-shared V/K, partial flash over j-slice ----------------
// grid 256 = 32 q-groups (256 q) x 8 j-slices (1024 j). Block: 16 waves, wave w
// owns q rows [qg*256 + w*16, +16). Per 32-j tile: 288 threads stage V(64x32) +
// K(32x8) bf16 into double-buffered LDS (one 16B chunk each, reg-prefetched);
// all waves consume via ds_read (bank-uniform, conflict-free). 1 barrier/iter.
// Partial numerators/denoms -> global; merged by attn_merge_k.
__global__ __launch_bounds__(1024) void attn_part_k(
    const ushort_t* __restrict__ Qb, const ushort_t* __restrict__ Kb,
    const ushort_t* __restrict__ VT, float* __restrict__ Pnum,
    float* __restrict__ Pden)
{
  const int tid = threadIdx.x;
  const int wave = tid >> 6, lane = tid & 63;
  const int m = lane & 15, g = lane >> 4;
  const int qg = blockIdx.x >> 3, js = blockIdx.x & 7;
  const int q0 = qg * 256 + wave * 16;
  const int j0 = js * 1024;
  const f32x4 zero4 = {0.f,0.f,0.f,0.f};

  __shared__ ushort_t Vls[2][64][32];
  __shared__ ushort_t Kls[2][32][8];

  const bool isV = (tid < 256);
  const int vd = tid >> 2, vc = tid & 3;
  const bool isK = (tid >= 256 && tid < 288);
  const int kj = tid - 256;

  short8 vreg = {0,0,0,0,0,0,0,0}, kreg = {0,0,0,0,0,0,0,0};
  auto LOAD = [&](int jb) {
    if (isV) vreg = *(const short8*)&VT[(size_t)vd * 8192 + jb + vc * 8];
    if (isK) kreg = *(const short8*)&Kb[(size_t)(jb + kj) * 8];
  };
  auto WRITE = [&](int cur) {
    if (isV) *(short8*)&Vls[cur][vd][vc * 8] = vreg;
    if (isK) *(short8*)&Kls[cur][kj][0] = kreg;
  };

  short8 qf = {0,0,0,0,0,0,0,0};
  if (lane < 16) qf = *(const short8*)&Qb[(size_t)(q0 + m) * 8];

  f32x4 acc[4];
  #pragma unroll
  for (int dt=0;dt<4;dt++) acc[dt] = zero4;
  float lsum = 0.f;

  LOAD(j0);
  int cur = 0;
  for (int it = 0; it < 32; ++it) {
    WRITE(cur);
    __syncthreads();
    if (it + 1 < 32) LOAD(j0 + (it + 1) * 32);

    short8 kf0 = {0,0,0,0,0,0,0,0}, kf1 = {0,0,0,0,0,0,0,0};
    if (lane < 16) {
      kf0 = *(const short8*)&Kls[cur][m][0];
      kf1 = *(const short8*)&Kls[cur][16 + m][0];
    }
    const f32x4 s0 = __builtin_amdgcn_mfma_f32_16x16x32_bf16(kf0, qf, zero4, 0,0,0);
    const f32x4 s1 = __builtin_amdgcn_mfma_f32_16x16x32_bf16(kf1, qf, zero4, 0,0,0);
    const float e00 = __expf(s0[0]), e01 = __expf(s0[1]), e02 = __expf(s0[2]), e03 = __expf(s0[3]);
    const float e10 = __expf(s1[0]), e11 = __expf(s1[1]), e12 = __expf(s1[2]), e13 = __expf(s1[3]);
    lsum += ((e00+e01)+(e02+e03)) + ((e10+e11)+(e12+e13));
    unsigned X01 = bfpair(e00,e01), X23 = bfpair(e02,e03);
    unsigned Y01 = bfpair(e10,e11), Y23 = bfpair(e12,e13);
    permswap32(X01, Y01); permswap16(X01, Y01);
    permswap32(X23, Y23); permswap16(X23, Y23);
    union { unsigned u[4]; short8 s; } pfu;
    pfu.u[0] = X01;
    pfu.u[1] = X23;
    pfu.u[2] = Y01;
    pfu.u[3] = Y23;
    #pragma unroll
    for (int dt=0;dt<4;dt++) {
      const short8 vf = *(const short8*)&Vls[cur][dt*16 + m][g * 8];
      acc[dt] = __builtin_amdgcn_mfma_f32_16x16x32_bf16(pfu.s, vf, acc[dt], 0,0,0);
    }
    cur ^= 1;
  }

  lsum += __shfl_xor(lsum, 16, 64);
  lsum += __shfl_xor(lsum, 32, 64);

  float* np = &Pnum[((size_t)blockIdx.x * 256 + wave * 16) * 64];
  #pragma unroll
  for (int dt=0;dt<4;dt++)
    #pragma unroll
    for (int r=0;r<4;r++)
      np[(size_t)(4*g + r) * 64 + dt*16 + m] = acc[dt][r];
  if (lane < 16)
    Pden[(size_t)blockIdx.x * 256 + wave * 16 + m] = lsum;
}

// ---------------- attention pass 2: merge j-slices + residual ----------------
__global__ __launch_bounds__(256) void attn_merge_k(
    const float* __restrict__ Pnum, const float* __restrict__ Pden,
    const float* __restrict__ H3, const float* __restrict__ gamma,
    float* __restrict__ Hatt, ushort_t* __restrict__ Hab)
{
  const int wave = threadIdx.x >> 6, lane = threadIdx.x & 63;
  const int q = blockIdx.x * 4 + wave;
  const int qg = q >> 8, qloc = q & 255;
  float num = 0.f, den = 0.f;
  #pragma unroll
  for (int js = 0; js < 8; ++js) {
    const size_t base = (size_t)(qg * 8 + js) * 256 + qloc;
    num += Pnum[base * 64 + lane];
    den += Pden[base];
  }
  const float hv = fmaf(gamma[0], num / den, H3[(size_t)q * 64 + lane]);
  Hatt[(size_t)q * 64 + lane] = hv;
  Hab[(size_t)q * 64 + lane] = bf16of(hv);
}

// ---------------- fused MIL scores via MFMA ----------------
__global__ __launch_bounds__(64) void mil_fused_k(
    const ushort_t* __restrict__ Hab, const ushort_t* __restrict__ Wa1t,
    const float* __restrict__ ba1, const float* __restrict__ Wa2,
    const float* __restrict__ ba2, float* __restrict__ scores)
{
  const int lane = threadIdx.x;
  const int ln = lane & 15, g = lane >> 4;
  const int q0 = blockIdx.x * 16;
  const f32x4 zero4 = {0.f, 0.f, 0.f, 0.f};
  f32x4 acc[4];
  #pragma unroll
  for (int nt = 0; nt < 4; ++nt) acc[nt] = zero4;
  #pragma unroll
  for (int k0 = 0; k0 < 64; k0 += 32) {
    const short8 af = *(const short8*)&Hab[(size_t)(q0 + ln) * 64 + k0 + g * 8];
    #pragma unroll
    for (int nt = 0; nt < 4; ++nt) {
      const short8 bfr = *(const short8*)&Wa1t[(size_t)(nt * 16 + ln) * 64 + k0 + g * 8];
      acc[nt] = __builtin_amdgcn_mfma_f32_16x16x32_bf16(af, bfr, acc[nt], 0, 0, 0);
    }
  }
  #pragma unroll
  for (int r = 0; r < 4; ++r) {
    float s = 0.f;
    #pragma unroll
    for (int nt = 0; nt < 4; ++nt) {
      const int n = nt * 16 + ln;
      s += tanhf(acc[nt][r] + ba1[n]) * Wa2[n];
    }
    s += __shfl_xor(s, 1, 64); s += __shfl_xor(s, 2, 64);
    s += __shfl_xor(s, 4, 64); s += __shfl_xor(s, 8, 64);
    if (ln == 0) scores[q0 + 4 * g + r] = s + ba2[0];
  }
}

// ---------------- pooling stage 1 ----------------
__global__ __launch_bounds__(256) void pool1_k(
    const float* __restrict__ Hm, const float* __restrict__ scores,
    float* __restrict__ pM, float* __restrict__ pS)
{
  const int wave = threadIdx.x >> 6, lane = threadIdx.x & 63;
  const int b = blockIdx.x;
  float macc = 0.f, se = 0.f;
  for (int t=0;t<32;t++) {
    const int i = b*128 + wave*32 + t;
    const float e = __expf(scores[i]);
    se += e;
    macc = fmaf(e, Hm[(size_t)i*64 + lane], macc);
  }
  __shared__ float Ms[4][64];
  __shared__ float Ss[4];
  Ms[wave][lane] = macc;
  if (lane == 0) Ss[wave] = se;
  __syncthreads();
  if (wave == 0) {
    pM[b*64 + lane] = Ms[0][lane]+Ms[1][lane]+Ms[2][lane]+Ms[3][lane];
    if (lane == 0) pS[b] = Ss[0]+Ss[1]+Ss[2]+Ss[3];
  }
}

// ---------------- pooling stage 2 ----------------
__global__ void pool2_k(const float* __restrict__ pM, const float* __restrict__ pS,
                        const float* __restrict__ Wc, const float* __restrict__ bc,
                        float* __restrict__ out)
{
  const int lane = threadIdx.x;
  float s_ = pS[lane];
  s_ += __shfl_xor(s_,1,64);  s_ += __shfl_xor(s_,2,64);
  s_ += __shfl_xor(s_,4,64);  s_ += __shfl_xor(s_,8,64);
  s_ += __shfl_xor(s_,16,64); s_ += __shfl_xor(s_,32,64);
  float m_ = 0.f;
  for (int b=0;b<64;b++) m_ += pM[b*64+lane];
  const float Md = m_ / s_;
  out[1+lane] = Md;
  float yp = Md * Wc[lane];
  yp += __shfl_xor(yp,1,64);  yp += __shfl_xor(yp,2,64);
  yp += __shfl_xor(yp,4,64);  yp += __shfl_xor(yp,8,64);
  yp += __shfl_xor(yp,16,64); yp += __shfl_xor(yp,32,64);
  if (lane == 0) {
    float y = 1.f/(1.f + __expf(-(yp + bc[0])));
    y = fminf(fmaxf(y, 1e-5f), 1.f - 1e-5f);
    out[0] = y;
  }
}

extern "C" void kernel_launch(void* const* d_in, const int* in_sizes, int n_in,
                              void* d_out, int out_size, void* d_ws, size_t ws_size,
                              hipStream_t stream)
{
  const float* x    = (const float*)d_in[0];
  const float* W1   = (const float*)d_in[1];
  const float* b1   = (const float*)d_in[2];
  const float* W2   = (const float*)d_in[3];
  const float* b2   = (const float*)d_in[4];
  const float* W3   = (const float*)d_in[5];
  const float* b3   = (const float*)d_in[6];
  const float* Wq   = (const float*)d_in[7];
  const float* bq   = (const float*)d_in[8];
  const float* Wk   = (const float*)d_in[9];
  const float* bk   = (const float*)d_in[10];
  const float* Wv   = (const float*)d_in[11];
  const float* bv   = (const float*)d_in[12];
  const float* gam  = (const float*)d_in[13];
  const float* Wa1  = (const float*)d_in[14];
  const float* ba1  = (const float*)d_in[15];
  const float* Wa2  = (const float*)d_in[16];
  const float* ba2  = (const float*)d_in[17];
  const float* Wc   = (const float*)d_in[18];
  const float* bc   = (const float*)d_in[19];
  float* out = (float*)d_out;

  char* w = (char*)d_ws;
  float* H3 = (float*)w;        w += (size_t)8192*64*4;
  float* Ha = (float*)w;        w += (size_t)8192*64*4;
  float* sc = (float*)w;        w += 8192*4;
  float* pM = (float*)w;        w += 64*64*4;
  float* pS = (float*)w;        w += 64*4;
  float* Pnum = (float*)w;      w += (size_t)256*256*64*4;
  float* Pden = (float*)w;      w += (size_t)256*256*4;
  ushort_t* H1b = (ushort_t*)w; w += (size_t)8192*256*2;
  ushort_t* H2b = (ushort_t*)w; w += (size_t)8192*128*2;
  ushort_t* H3b = (ushort_t*)w; w += (size_t)8192*64*2;
  ushort_t* Hab = (ushort_t*)w; w += (size_t)8192*64*2;
  ushort_t* Qb  = (ushort_t*)w; w += (size_t)8192*8*2;
  ushort_t* Kb  = (ushort_t*)w; w += (size_t)8192*8*2;
  ushort_t* VT  = (ushort_t*)w; w += (size_t)64*8192*2;
  ushort_t* W1t = (ushort_t*)w; w += (size_t)256*1024*2;
  ushort_t* W2t = (ushort_t*)w; w += (size_t)128*256*2;
  ushort_t* W3t = (ushort_t*)w; w += (size_t)64*128*2;
  ushort_t* Wa1t= (ushort_t*)w; w += (size_t)64*64*2;
  ushort_t* Wqkv= (ushort_t*)w; w += (size_t)80*64*2;

  transpose_bf16_k<<<dim3(256/32, 1024/32), 256, 0, stream>>>(W1, W1t, 1024, 256);
  transpose_bf16_k<<<dim3(128/32,  256/32), 256, 0, stream>>>(W2, W2t,  256, 128);
  transpose_bf16_k<<<dim3( 64/32,  128/32), 256, 0, stream>>>(W3, W3t,  128,  64);
  transpose_bf16_k<<<dim3( 64/32,   64/32), 256, 0, stream>>>(Wa1, Wa1t,  64,  64);
  prep_qkvw_k<<<1, 256, 0, stream>>>(Wq, Wk, Wv, Wqkv);

  gemm_staged<1024,256,16,true ,0><<<256, 1024, 0, stream>>>(x,   W1t, b1, H1b, nullptr);
  gemm_staged< 256,128, 8,false,0><<<256,  512, 0, stream>>>(H1b, W2t, b2, H2b, nullptr);
  gemm_mfma< 128, 64,1,false,2><<<512, 256, 0, stream>>>(H2b, W3t, b3, H3, H3b);

  qkv_fused_k<<<512, 64, 0, stream>>>(H3b, Wqkv, bq, bk, bv, Qb, Kb, VT);
  attn_part_k<<<256, 1024, 0, stream>>>(Qb, Kb, VT, Pnum, Pden);
  attn_merge_k<<<2048, 256, 0, stream>>>(Pnum, Pden, H3, gam, Ha, Hab);
  mil_fused_k<<<512, 64, 0, stream>>>(Hab, Wa1t, ba1, Wa2, ba2, sc);
  pool1_k<<<64, 256, 0, stream>>>(Ha, sc, pM, pS);
  pool2_k<<<1, 64, 0, stream>>>(pM, pS, Wc, bc, out);
}

// Round 11
// 82.316 us; speedup vs baseline: 1.5798x; 1.1512x over previous
//
#include <hip/hip_runtime.h>
#include <math.h>

typedef unsigned short ushort_t;
typedef __attribute__((ext_vector_type(8))) short short8;
typedef __attribute__((ext_vector_type(4))) float f32x4;

__device__ inline unsigned bfpair(float lo, float hi) {
  unsigned r;
  asm("v_cvt_pk_bf16_f32 %0, %1, %2" : "=v"(r) : "v"(lo), "v"(hi));
  return r;
}
__device__ inline ushort_t bf16of(float v) { return (ushort_t)(bfpair(v, v) & 0xffffu); }
__device__ inline void permswap32(unsigned &a, unsigned &b) {
  asm("v_permlane32_swap_b32 %0, %1" : "+v"(a), "+v"(b));
}
__device__ inline void permswap16(unsigned &a, unsigned &b) {
  asm("v_permlane16_swap_b32 %0, %1" : "+v"(a), "+v"(b));
}

// ---------------- fused prep: all weight transposes + qkv pack in ONE launch ----------------
__device__ void transpose_tile(const float* __restrict__ W, ushort_t* __restrict__ Wt,
                               int K, int N, int bx, int by, int t)
{
  __shared__ float Ls[32][33];
  const int n0 = bx * 32, k0 = by * 32;
  const int tx = t & 31, tyb = t >> 5;
  #pragma unroll
  for (int s = 0; s < 4; ++s) {
    const int k = tyb + s * 8;
    Ls[k][tx] = W[(size_t)(k0 + k) * N + n0 + tx];
  }
  __syncthreads();
  #pragma unroll
  for (int s = 0; s < 2; ++s) {
    const int idx = t + 256 * s;
    const int n = idx >> 4, kk = (idx & 15) * 2;
    const unsigned pk = bfpair(Ls[kk][n], Ls[kk + 1][n]);
    *(unsigned*)&Wt[(size_t)(n0 + n) * K + k0 + kk] = pk;
  }
}

__global__ __launch_bounds__(256) void prep_all_k(
    const float* __restrict__ W1, ushort_t* __restrict__ W1t,
    const float* __restrict__ W2, ushort_t* __restrict__ W2t,
    const float* __restrict__ W3, ushort_t* __restrict__ W3t,
    const float* __restrict__ Wa1, ushort_t* __restrict__ Wa1t,
    const float* __restrict__ Wq, const float* __restrict__ Wk,
    const float* __restrict__ Wv, ushort_t* __restrict__ WqkvT)
{
  const int bid = blockIdx.x;
  const int t = threadIdx.x;
  if (bid < 256)      { transpose_tile(W1, W1t, 1024, 256, bid & 7, bid >> 3, t); }
  else if (bid < 288) { const int l = bid - 256; transpose_tile(W2, W2t, 256, 128, l & 3, l >> 2, t); }
  else if (bid < 296) { const int l = bid - 288; transpose_tile(W3, W3t, 128,  64, l & 1, l >> 1, t); }
  else if (bid < 300) { const int l = bid - 296; transpose_tile(Wa1, Wa1t, 64,  64, l & 1, l >> 1, t); }
  else {
    for (int e = t; e < 80 * 64; e += 256) {
      const int j = e >> 6, k = e & 63;
      float v;
      if (j < 8)       v = Wq[k * 8 + j];
      else if (j < 16) v = Wk[k * 8 + (j - 8)];
      else             v = Wv[k * 64 + (j - 16)];
      WqkvT[e] = bf16of(v);
    }
  }
}

// ---------------- LDS-staged pipelined bf16 MFMA GEMM + bias + relu (R9-verified) ----------------
template<int K, int N, int WAVES, bool A_FP32, int OMODE>
__global__ __launch_bounds__(WAVES * 64) void gemm_staged(
    const void* __restrict__ Ap, const ushort_t* __restrict__ Wt,
    const float* __restrict__ bias, void* __restrict__ C0, void* __restrict__ C1)
{
  constexpr int BM = 32;
  constexpr int NWN = N / 32;
  constexpr int NK = K / 32;
  constexpr int A_CH = BM * 4;
  constexpr int B_CH = N * 4;
  static_assert(WAVES * 64 == B_CH, "threads must equal B chunk count");
  static_assert(A_CH <= WAVES * 64, "");

  const int tid = threadIdx.x;
  const int wave = tid >> 6, lane = tid & 63;
  const int ln = lane & 15, g = lane >> 4;
  const int wm = wave / NWN, wn = wave % NWN;
  const int bm0 = blockIdx.x * BM;

  __shared__ ushort_t Als[2][BM][40];
  __shared__ ushort_t Bls[2][N][40];

  const float* Af = (const float*)Ap;
  const ushort_t* Ab = (const ushort_t*)Ap;

  const bool hasA = (tid < A_CH);
  const int arow = tid >> 2, akq = tid & 3;
  const int bc = hasA ? (B_CH - A_CH + tid) : (tid - A_CH);
  const int brow = bc >> 2, bkq = bc & 3;

  float4 rf0, rf1;
  short8 ra, rb;

  auto LOADK = [&](int ks) {
    const int k0 = ks * 32;
    if (hasA) {
      if (A_FP32) {
        const float* src = &Af[(size_t)(bm0 + arow) * K + k0 + akq * 8];
        rf0 = *(const float4*)src;
        rf1 = *(const float4*)(src + 4);
      } else {
        ra = *(const short8*)&Ab[(size_t)(bm0 + arow) * K + k0 + akq * 8];
      }
    }
    rb = *(const short8*)&Wt[(size_t)brow * K + k0 + bkq * 8];
  };
  auto WRITEK = [&](int cur) {
    if (hasA) {
      short8 wa;
      if (A_FP32) {
        union { unsigned u[4]; short8 s8; } cv;
        cv.u[0] = bfpair(rf0.x, rf0.y);
        cv.u[1] = bfpair(rf0.z, rf0.w);
        cv.u[2] = bfpair(rf1.x, rf1.y);
        cv.u[3] = bfpair(rf1.z, rf1.w);
        wa = cv.s8;
      } else {
        wa = ra;
      }
      *(short8*)&Als[cur][arow][akq * 8] = wa;
    }
    *(short8*)&Bls[cur][brow][bkq * 8] = rb;
  };

  f32x4 acc0 = {0.f, 0.f, 0.f, 0.f};
  f32x4 acc1 = {0.f, 0.f, 0.f, 0.f};

  LOADK(0);
  int cur = 0;
  for (int ks = 0; ks < NK; ++ks) {
    WRITEK(cur);
    __syncthreads();
    if (ks + 1 < NK) LOADK(ks + 1);
    const short8 af = *(const short8*)&Als[cur][wm * 16 + ln][g * 8];
    const short8 b0 = *(const short8*)&Bls[cur][wn * 32 + ln][g * 8];
    const short8 b1 = *(const short8*)&Bls[cur][wn * 32 + 16 + ln][g * 8];
    acc0 = __builtin_amdgcn_mfma_f32_16x16x32_bf16(af, b0, acc0, 0, 0, 0);
    acc1 = __builtin_amdgcn_mfma_f32_16x16x32_bf16(af, b1, acc1, 0, 0, 0);
    cur ^= 1;
  }

  #pragma unroll
  for (int nt = 0; nt < 2; ++nt) {
    const f32x4 a = nt ? acc1 : acc0;
    #pragma unroll
    for (int r = 0; r < 4; ++r) {
      const int m = bm0 + wm * 16 + 4 * g + r;
      const int n = wn * 32 + nt * 16 + ln;
      float v = a[r] + bias[n];
      v = fmaxf(v, 0.f);
      if (OMODE == 0) {
        ((ushort_t*)C0)[(size_t)m * N + n] = bf16of(v);
      } else {
        ((float*)C0)[(size_t)m * N + n] = v;
      }
    }
  }
}

// ---------------- fused gemm3 + QKV (one block = 16 rows) ----------------
// Part 1: H3 = relu(H2b @ W3t + b3) (4 waves x 16 cols), f32 to global + bf16 to LDS.
// Part 2: QKV from LDS: wave0 -> Q/K tile + V tile0, waves 1-3 -> V tiles 1-3.
__global__ __launch_bounds__(256) void gemm3_qkv_k(
    const ushort_t* __restrict__ H2b, const ushort_t* __restrict__ W3t,
    const float* __restrict__ b3, const ushort_t* __restrict__ WqkvT,
    const float* __restrict__ bq, const float* __restrict__ bk, const float* __restrict__ bv,
    float* __restrict__ H3, ushort_t* __restrict__ Qb, ushort_t* __restrict__ Kb,
    ushort_t* __restrict__ VT)
{
  const int wave = threadIdx.x >> 6, lane = threadIdx.x & 63;
  const int ln = lane & 15, g = lane >> 4;
  const int q0 = blockIdx.x * 16;
  const f32x4 zero4 = {0.f, 0.f, 0.f, 0.f};

  __shared__ ushort_t Hls[16][72];

  // part 1: gemm3
  f32x4 acc = zero4;
  #pragma unroll
  for (int k0 = 0; k0 < 128; k0 += 32) {
    const short8 af = *(const short8*)&H2b[(size_t)(q0 + ln) * 128 + k0 + g * 8];
    const short8 bfr = *(const short8*)&W3t[(size_t)(wave * 16 + ln) * 128 + k0 + g * 8];
    acc = __builtin_amdgcn_mfma_f32_16x16x32_bf16(af, bfr, acc, 0, 0, 0);
  }
  #pragma unroll
  for (int r = 0; r < 4; ++r) {
    const int m = q0 + 4 * g + r;
    const int n = wave * 16 + ln;
    float v = fmaxf(acc[r] + b3[n], 0.f);
    H3[(size_t)m * 64 + n] = v;
    Hls[4 * g + r][n] = bf16of(v);
  }
  __syncthreads();

  // part 2: qkv. wave w handles nt set: w0:{0,1}, w1:{2}, w2:{3}, w3:{4}
  const int ntA = (wave == 0) ? 0 : (wave + 1);
  f32x4 accA = zero4, accB = zero4;
  #pragma unroll
  for (int k0 = 0; k0 < 64; k0 += 32) {
    const short8 af = *(const short8*)&Hls[ln][k0 + g * 8];
    const short8 bA = *(const short8*)&WqkvT[(size_t)(ntA * 16 + ln) * 64 + k0 + g * 8];
    accA = __builtin_amdgcn_mfma_f32_16x16x32_bf16(af, bA, accA, 0, 0, 0);
    if (wave == 0) {
      const short8 bB = *(const short8*)&WqkvT[(size_t)(16 + ln) * 64 + k0 + g * 8];
      accB = __builtin_amdgcn_mfma_f32_16x16x32_bf16(af, bB, accB, 0, 0, 0);
    }
  }
  if (wave == 0) {
    // accA = nt0: Q (ln<8) / K (ln>=8)
    const float b0 = (ln < 8) ? bq[ln] : bk[ln - 8];
    #pragma unroll
    for (int r = 0; r < 4; ++r) {
      const int m = q0 + 4 * g + r;
      const float v = accA[r] + b0;
      if (ln < 8) Qb[(size_t)m * 8 + ln] = bf16of(v);
      else        Kb[(size_t)m * 8 + (ln - 8)] = bf16of(v);
    }
    // accB = V dims 0..15
    const int d = ln;
    const float bb = bv[d];
    uint2 o;
    o.x = bfpair(accB[0] + bb, accB[1] + bb);
    o.y = bfpair(accB[2] + bb, accB[3] + bb);
    *(uint2*)&VT[(size_t)d * 8192 + q0 + 4 * g] = o;
  } else {
    const int d = (ntA - 1) * 16 + ln;
    const float bb = bv[d];
    uint2 o;
    o.x = bfpair(accA[0] + bb, accA[1] + bb);
    o.y = bfpair(accA[2] + bb, accA[3] + bb);
    *(uint2*)&VT[(size_t)d * 8192 + q0 + 4 * g] = o;
  }
}

// ---------------- attention pass 1: LDS-shared V/K (padded, 64-j double-stage) ----------------
// grid 256 = 32 q-groups (256 q) x 8 j-slices (1024 j). 16 waves, wave owns 16 q.
// Per 64-j tile: 576 threads stage V(64x64)+K(64x8) into padded double-buffered LDS
// (rows padded: V 68, K 12 shorts -> conflict-free b128 reads). 1 barrier / 64 j.
__global__ __launch_bounds__(1024) void attn_part_k(
    const ushort_t* __restrict__ Qb, const ushort_t* __restrict__ Kb,
    const ushort_t* __restrict__ VT, float* __restrict__ Pnum,
    float* __restrict__ Pden)
{
  const int tid = threadIdx.x;
  const int wave = tid >> 6, lane = tid & 63;
  const int m = lane & 15, g = lane >> 4;
  const int qg = blockIdx.x >> 3, js = blockIdx.x & 7;
  const int q0 = qg * 256 + wave * 16;
  const int j0 = js * 1024;
  const f32x4 zero4 = {0.f,0.f,0.f,0.f};

  __shared__ ushort_t Vls[2][64][68];
  __shared__ ushort_t Kls[2][64][12];

  const bool isV = (tid < 512);
  const int vd = tid >> 3, vc = tid & 7;
  const bool isK = (tid >= 512 && tid < 576);
  const int kj = tid - 512;

  short8 vreg = {0,0,0,0,0,0,0,0}, kreg = {0,0,0,0,0,0,0,0};
  auto LOAD = [&](int jb) {
    if (isV) vreg = *(const short8*)&VT[(size_t)vd * 8192 + jb + vc * 8];
    if (isK) kreg = *(const short8*)&Kb[(size_t)(jb + kj) * 8];
  };
  auto WRITE = [&](int cur) {
    if (isV) *(short8*)&Vls[cur][vd][vc * 8] = vreg;
    if (isK) *(short8*)&Kls[cur][kj][0] = kreg;
  };

  short8 qf = {0,0,0,0,0,0,0,0};
  if (lane < 16) qf = *(const short8*)&Qb[(size_t)(q0 + m) * 8];

  f32x4 acc[4];
  #pragma unroll
  for (int dt=0;dt<4;dt++) acc[dt] = zero4;
  float lsum = 0.f;

  LOAD(j0);
  int cur = 0;
  for (int it = 0; it < 16; ++it) {
    WRITE(cur);
    __syncthreads();
    if (it + 1 < 16) LOAD(j0 + (it + 1) * 64);

    #pragma unroll
    for (int half = 0; half < 2; ++half) {
      short8 kf0 = {0,0,0,0,0,0,0,0}, kf1 = {0,0,0,0,0,0,0,0};
      if (lane < 16) {
        kf0 = *(const short8*)&Kls[cur][half*32 + m][0];
        kf1 = *(const short8*)&Kls[cur][half*32 + 16 + m][0];
      }
      const f32x4 s0 = __builtin_amdgcn_mfma_f32_16x16x32_bf16(kf0, qf, zero4, 0,0,0);
      const f32x4 s1 = __builtin_amdgcn_mfma_f32_16x16x32_bf16(kf1, qf, zero4, 0,0,0);
      const float e00 = __expf(s0[0]), e01 = __expf(s0[1]), e02 = __expf(s0[2]), e03 = __expf(s0[3]);
      const float e10 = __expf(s1[0]), e11 = __expf(s1[1]), e12 = __expf(s1[2]), e13 = __expf(s1[3]);
      lsum += ((e00+e01)+(e02+e03)) + ((e10+e11)+(e12+e13));
      unsigned X01 = bfpair(e00,e01), X23 = bfpair(e02,e03);
      unsigned Y01 = bfpair(e10,e11), Y23 = bfpair(e12,e13);
      permswap32(X01, Y01); permswap16(X01, Y01);
      permswap32(X23, Y23); permswap16(X23, Y23);
      union { unsigned u[4]; short8 s; } pfu;
      pfu.u[0] = X01;
      pfu.u[1] = X23;
      pfu.u[2] = Y01;
      pfu.u[3] = Y23;
      #pragma unroll
      for (int dt=0;dt<4;dt++) {
        const short8 vf = *(const short8*)&Vls[cur][dt*16 + m][half*32 + g * 8];
        acc[dt] = __builtin_amdgcn_mfma_f32_16x16x32_bf16(pfu.s, vf, acc[dt], 0,0,0);
      }
    }
    cur ^= 1;
  }

  lsum += __shfl_xor(lsum, 16, 64);
  lsum += __shfl_xor(lsum, 32, 64);

  float* np = &Pnum[((size_t)blockIdx.x * 256 + wave * 16) * 64];
  #pragma unroll
  for (int dt=0;dt<4;dt++)
    #pragma unroll
    for (int r=0;r<4;r++)
      np[(size_t)(4*g + r) * 64 + dt*16 + m] = acc[dt][r];
  if (lane < 16)
    Pden[(size_t)blockIdx.x * 256 + wave * 16 + m] = lsum;
}

// ---------------- attention pass 2: merge j-slices + residual ----------------
__global__ __launch_bounds__(256) void attn_merge_k(
    const float* __restrict__ Pnum, const float* __restrict__ Pden,
    const float* __restrict__ H3, const float* __restrict__ gamma,
    float* __restrict__ Hatt, ushort_t* __restrict__ Hab)
{
  const int wave = threadIdx.x >> 6, lane = threadIdx.x & 63;
  const int q = blockIdx.x * 4 + wave;
  const int qg = q >> 8, qloc = q & 255;
  float num = 0.f, den = 0.f;
  #pragma unroll
  for (int js = 0; js < 8; ++js) {
    const size_t base = (size_t)(qg * 8 + js) * 256 + qloc;
    num += Pnum[base * 64 + lane];
    den += Pden[base];
  }
  const float hv = fmaf(gamma[0], num / den, H3[(size_t)q * 64 + lane]);
  Hatt[(size_t)q * 64 + lane] = hv;
  Hab[(size_t)q * 64 + lane] = bf16of(hv);
}

// ---------------- fused MIL scores via MFMA ----------------
__global__ __launch_bounds__(64) void mil_fused_k(
    const ushort_t* __restrict__ Hab, const ushort_t* __restrict__ Wa1t,
    const float* __restrict__ ba1, const float* __restrict__ Wa2,
    const float* __restrict__ ba2, float* __restrict__ scores)
{
  const int lane = threadIdx.x;
  const int ln = lane & 15, g = lane >> 4;
  const int q0 = blockIdx.x * 16;
  const f32x4 zero4 = {0.f, 0.f, 0.f, 0.f};
  f32x4 acc[4];
  #pragma unroll
  for (int nt = 0; nt < 4; ++nt) acc[nt] = zero4;
  #pragma unroll
  for (int k0 = 0; k0 < 64; k0 += 32) {
    const short8 af = *(const short8*)&Hab[(size_t)(q0 + ln) * 64 + k0 + g * 8];
    #pragma unroll
    for (int nt = 0; nt < 4; ++nt) {
      const short8 bfr = *(const short8*)&Wa1t[(size_t)(nt * 16 + ln) * 64 + k0 + g * 8];
      acc[nt] = __builtin_amdgcn_mfma_f32_16x16x32_bf16(af, bfr, acc[nt], 0, 0, 0);
    }
  }
  #pragma unroll
  for (int r = 0; r < 4; ++r) {
    float s = 0.f;
    #pragma unroll
    for (int nt = 0; nt < 4; ++nt) {
      const int n = nt * 16 + ln;
      s += tanhf(acc[nt][r] + ba1[n]) * Wa2[n];
    }
    s += __shfl_xor(s, 1, 64); s += __shfl_xor(s, 2, 64);
    s += __shfl_xor(s, 4, 64); s += __shfl_xor(s, 8, 64);
    if (ln == 0) scores[q0 + 4 * g + r] = s + ba2[0];
  }
}

// ---------------- pooling stage 1 ----------------
__global__ __launch_bounds__(256) void pool1_k(
    const float* __restrict__ Hm, const float* __restrict__ scores,
    float* __restrict__ pM, float* __restrict__ pS)
{
  const int wave = threadIdx.x >> 6, lane = threadIdx.x & 63;
  const int b = blockIdx.x;
  float macc = 0.f, se = 0.f;
  for (int t=0;t<32;t++) {
    const int i = b*128 + wave*32 + t;
    const float e = __expf(scores[i]);
    se += e;
    macc = fmaf(e, Hm[(size_t)i*64 + lane], macc);
  }
  __shared__ float Ms[4][64];
  __shared__ float Ss[4];
  Ms[wave][lane] = macc;
  if (lane == 0) Ss[wave] = se;
  __syncthreads();
  if (wave == 0) {
    pM[b*64 + lane] = Ms[0][lane]+Ms[1][lane]+Ms[2][lane]+Ms[3][lane];
    if (lane == 0) pS[b] = Ss[0]+Ss[1]+Ss[2]+Ss[3];
  }
}

// ---------------- pooling stage 2 ----------------
__global__ void pool2_k(const float* __restrict__ pM, const float* __restrict__ pS,
                        const float* __restrict__ Wc, const float* __restrict__ bc,
                        float* __restrict__ out)
{
  const int lane = threadIdx.x;
  float s_ = pS[lane];
  s_ += __shfl_xor(s_,1,64);  s_ += __shfl_xor(s_,2,64);
  s_ += __shfl_xor(s_,4,64);  s_ += __shfl_xor(s_,8,64);
  s_ += __shfl_xor(s_,16,64); s_ += __shfl_xor(s_,32,64);
  float m_ = 0.f;
  for (int b=0;b<64;b++) m_ += pM[b*64+lane];
  const float Md = m_ / s_;
  out[1+lane] = Md;
  float yp = Md * Wc[lane];
  yp += __shfl_xor(yp,1,64);  yp += __shfl_xor(yp,2,64);
  yp += __shfl_xor(yp,4,64);  yp += __shfl_xor(yp,8,64);
  yp += __shfl_xor(yp,16,64); yp += __shfl_xor(yp,32,64);
  if (lane == 0) {
    float y = 1.f/(1.f + __expf(-(yp + bc[0])));
    y = fminf(fmaxf(y, 1e-5f), 1.f - 1e-5f);
    out[0] = y;
  }
}

extern "C" void kernel_launch(void* const* d_in, const int* in_sizes, int n_in,
                              void* d_out, int out_size, void* d_ws, size_t ws_size,
                              hipStream_t stream)
{
  const float* x    = (const float*)d_in[0];
  const float* W1   = (const float*)d_in[1];
  const float* b1   = (const float*)d_in[2];
  const float* W2   = (const float*)d_in[3];
  const float* b2   = (const float*)d_in[4];
  const float* W3   = (const float*)d_in[5];
  const float* b3   = (const float*)d_in[6];
  const float* Wq   = (const float*)d_in[7];
  const float* bq   = (const float*)d_in[8];
  const float* Wk   = (const float*)d_in[9];
  const float* bk   = (const float*)d_in[10];
  const float* Wv   = (const float*)d_in[11];
  const float* bv   = (const float*)d_in[12];
  const float* gam  = (const float*)d_in[13];
  const float* Wa1  = (const float*)d_in[14];
  const float* ba1  = (const float*)d_in[15];
  const float* Wa2  = (const float*)d_in[16];
  const float* ba2  = (const float*)d_in[17];
  const float* Wc   = (const float*)d_in[18];
  const float* bc   = (const float*)d_in[19];
  float* out = (float*)d_out;

  char* w = (char*)d_ws;
  float* H3 = (float*)w;        w += (size_t)8192*64*4;
  float* Ha = (float*)w;        w += (size_t)8192*64*4;
  float* sc = (float*)w;        w += 8192*4;
  float* pM = (float*)w;        w += 64*64*4;
  float* pS = (float*)w;        w += 64*4;
  float* Pnum = (float*)w;      w += (size_t)256*256*64*4;
  float* Pden = (float*)w;      w += (size_t)256*256*4;
  ushort_t* H1b = (ushort_t*)w; w += (size_t)8192*256*2;
  ushort_t* H2b = (ushort_t*)w; w += (size_t)8192*128*2;
  ushort_t* Hab = (ushort_t*)w; w += (size_t)8192*64*2;
  ushort_t* Qb  = (ushort_t*)w; w += (size_t)8192*8*2;
  ushort_t* Kb  = (ushort_t*)w; w += (size_t)8192*8*2;
  ushort_t* VT  = (ushort_t*)w; w += (size_t)64*8192*2;
  ushort_t* W1t = (ushort_t*)w; w += (size_t)256*1024*2;
  ushort_t* W2t = (ushort_t*)w; w += (size_t)128*256*2;
  ushort_t* W3t = (ushort_t*)w; w += (size_t)64*128*2;
  ushort_t* Wa1t= (ushort_t*)w; w += (size_t)64*64*2;
  ushort_t* Wqkv= (ushort_t*)w; w += (size_t)80*64*2;

  prep_all_k<<<301, 256, 0, stream>>>(W1, W1t, W2, W2t, W3, W3t, Wa1, Wa1t,
                                      Wq, Wk, Wv, Wqkv);

  gemm_staged<1024,256,16,true ,0><<<256, 1024, 0, stream>>>(x,   W1t, b1, H1b, nullptr);
  gemm_staged< 256,128, 8,false,0><<<256,  512, 0, stream>>>(H1b, W2t, b2, H2b, nullptr);
  gemm3_qkv_k<<<512, 256, 0, stream>>>(H2b, W3t, b3, Wqkv, bq, bk, bv, H3, Qb, Kb, VT);

  attn_part_k<<<256, 1024, 0, stream>>>(Qb, Kb, VT, Pnum, Pden);
  attn_merge_k<<<2048, 256, 0, stream>>>(Pnum, Pden, H3, gam, Ha, Hab);
  mil_fused_k<<<512, 64, 0, stream>>>(Hab, Wa1t, ba1, Wa2, ba2, sc);
  pool1_k<<<64, 256, 0, stream>>>(Ha, sc, pM, pS);
  pool2_k<<<1, 64, 0, stream>>>(pM, pS, Wc, bc, out);
}

// Round 12
// 79.004 us; speedup vs baseline: 1.6460x; 1.0419x over previous
//
#include <hip/hip_runtime.h>
#include <math.h>

typedef unsigned short ushort_t;
typedef __attribute__((ext_vector_type(8))) short short8;
typedef __attribute__((ext_vector_type(4))) float f32x4;

__device__ inline unsigned bfpair(float lo, float hi) {
  unsigned r;
  asm("v_cvt_pk_bf16_f32 %0, %1, %2" : "=v"(r) : "v"(lo), "v"(hi));
  return r;
}
__device__ inline ushort_t bf16of(float v) { return (ushort_t)(bfpair(v, v) & 0xffffu); }
__device__ inline void permswap32(unsigned &a, unsigned &b) {
  asm("v_permlane32_swap_b32 %0, %1" : "+v"(a), "+v"(b));
}
__device__ inline void permswap16(unsigned &a, unsigned &b) {
  asm("v_permlane16_swap_b32 %0, %1" : "+v"(a), "+v"(b));
}

// ---------------- fused prep: all weight transposes + qkv pack (R11-verified) ----------------
__device__ void transpose_tile(const float* __restrict__ W, ushort_t* __restrict__ Wt,
                               int K, int N, int bx, int by, int t)
{
  __shared__ float Ls[32][33];
  const int n0 = bx * 32, k0 = by * 32;
  const int tx = t & 31, tyb = t >> 5;
  #pragma unroll
  for (int s = 0; s < 4; ++s) {
    const int k = tyb + s * 8;
    Ls[k][tx] = W[(size_t)(k0 + k) * N + n0 + tx];
  }
  __syncthreads();
  #pragma unroll
  for (int s = 0; s < 2; ++s) {
    const int idx = t + 256 * s;
    const int n = idx >> 4, kk = (idx & 15) * 2;
    const unsigned pk = bfpair(Ls[kk][n], Ls[kk + 1][n]);
    *(unsigned*)&Wt[(size_t)(n0 + n) * K + k0 + kk] = pk;
  }
}

__global__ __launch_bounds__(256) void prep_all_k(
    const float* __restrict__ W1, ushort_t* __restrict__ W1t,
    const float* __restrict__ W2, ushort_t* __restrict__ W2t,
    const float* __restrict__ W3, ushort_t* __restrict__ W3t,
    const float* __restrict__ Wa1, ushort_t* __restrict__ Wa1t,
    const float* __restrict__ Wq, const float* __restrict__ Wk,
    const float* __restrict__ Wv, ushort_t* __restrict__ WqkvT)
{
  const int bid = blockIdx.x;
  const int t = threadIdx.x;
  if (bid < 256)      { transpose_tile(W1, W1t, 1024, 256, bid & 7, bid >> 3, t); }
  else if (bid < 288) { const int l = bid - 256; transpose_tile(W2, W2t, 256, 128, l & 3, l >> 2, t); }
  else if (bid < 296) { const int l = bid - 288; transpose_tile(W3, W3t, 128,  64, l & 1, l >> 1, t); }
  else if (bid < 300) { const int l = bid - 296; transpose_tile(Wa1, Wa1t, 64,  64, l & 1, l >> 1, t); }
  else {
    for (int e = t; e < 80 * 64; e += 256) {
      const int j = e >> 6, k = e & 63;
      float v;
      if (j < 8)       v = Wq[k * 8 + j];
      else if (j < 16) v = Wk[k * 8 + (j - 8)];
      else             v = Wv[k * 64 + (j - 16)];
      WqkvT[e] = bf16of(v);
    }
  }
}

// ---------------- LDS-staged pipelined bf16 MFMA GEMM + bias + relu (R9-verified) ----------------
template<int K, int N, int WAVES, bool A_FP32, int OMODE>
__global__ __launch_bounds__(WAVES * 64) void gemm_staged(
    const void* __restrict__ Ap, const ushort_t* __restrict__ Wt,
    const float* __restrict__ bias, void* __restrict__ C0, void* __restrict__ C1)
{
  constexpr int BM = 32;
  constexpr int NWN = N / 32;
  constexpr int NK = K / 32;
  constexpr int A_CH = BM * 4;
  constexpr int B_CH = N * 4;
  static_assert(WAVES * 64 == B_CH, "threads must equal B chunk count");
  static_assert(A_CH <= WAVES * 64, "");

  const int tid = threadIdx.x;
  const int wave = tid >> 6, lane = tid & 63;
  const int ln = lane & 15, g = lane >> 4;
  const int wm = wave / NWN, wn = wave % NWN;
  const int bm0 = blockIdx.x * BM;

  __shared__ ushort_t Als[2][BM][40];
  __shared__ ushort_t Bls[2][N][40];

  const float* Af = (const float*)Ap;
  const ushort_t* Ab = (const ushort_t*)Ap;

  const bool hasA = (tid < A_CH);
  const int arow = tid >> 2, akq = tid & 3;
  const int bc = hasA ? (B_CH - A_CH + tid) : (tid - A_CH);
  const int brow = bc >> 2, bkq = bc & 3;

  float4 rf0, rf1;
  short8 ra, rb;

  auto LOADK = [&](int ks) {
    const int k0 = ks * 32;
    if (hasA) {
      if (A_FP32) {
        const float* src = &Af[(size_t)(bm0 + arow) * K + k0 + akq * 8];
        rf0 = *(const float4*)src;
        rf1 = *(const float4*)(src + 4);
      } else {
        ra = *(const short8*)&Ab[(size_t)(bm0 + arow) * K + k0 + akq * 8];
      }
    }
    rb = *(const short8*)&Wt[(size_t)brow * K + k0 + bkq * 8];
  };
  auto WRITEK = [&](int cur) {
    if (hasA) {
      short8 wa;
      if (A_FP32) {
        union { unsigned u[4]; short8 s8; } cv;
        cv.u[0] = bfpair(rf0.x, rf0.y);
        cv.u[1] = bfpair(rf0.z, rf0.w);
        cv.u[2] = bfpair(rf1.x, rf1.y);
        cv.u[3] = bfpair(rf1.z, rf1.w);
        wa = cv.s8;
      } else {
        wa = ra;
      }
      *(short8*)&Als[cur][arow][akq * 8] = wa;
    }
    *(short8*)&Bls[cur][brow][bkq * 8] = rb;
  };

  f32x4 acc0 = {0.f, 0.f, 0.f, 0.f};
  f32x4 acc1 = {0.f, 0.f, 0.f, 0.f};

  LOADK(0);
  int cur = 0;
  for (int ks = 0; ks < NK; ++ks) {
    WRITEK(cur);
    __syncthreads();
    if (ks + 1 < NK) LOADK(ks + 1);
    const short8 af = *(const short8*)&Als[cur][wm * 16 + ln][g * 8];
    const short8 b0 = *(const short8*)&Bls[cur][wn * 32 + ln][g * 8];
    const short8 b1 = *(const short8*)&Bls[cur][wn * 32 + 16 + ln][g * 8];
    acc0 = __builtin_amdgcn_mfma_f32_16x16x32_bf16(af, b0, acc0, 0, 0, 0);
    acc1 = __builtin_amdgcn_mfma_f32_16x16x32_bf16(af, b1, acc1, 0, 0, 0);
    cur ^= 1;
  }

  #pragma unroll
  for (int nt = 0; nt < 2; ++nt) {
    const f32x4 a = nt ? acc1 : acc0;
    #pragma unroll
    for (int r = 0; r < 4; ++r) {
      const int m = bm0 + wm * 16 + 4 * g + r;
      const int n = wn * 32 + nt * 16 + ln;
      float v = a[r] + bias[n];
      v = fmaxf(v, 0.f);
      if (OMODE == 0) {
        ((ushort_t*)C0)[(size_t)m * N + n] = bf16of(v);
      } else {
        ((float*)C0)[(size_t)m * N + n] = v;
      }
    }
  }
}

// ---------------- fused gemm2 + gemm3 + QKV (one block = 16 rows, 4 waves) ----------------
// gemm2: H2 = relu(H1b@W2t+b2) -> LDS [16][136] (uniform-8 bank pattern);
// gemm3: H3 = relu(H2ls@W3t+b3) -> f32 global + bf16 LDS [16][72];
// qkv:   Q/K/V^T from Hls (R10/11-verified epilogue).
__global__ __launch_bounds__(256) void mlp23_qkv_k(
    const ushort_t* __restrict__ H1b, const ushort_t* __restrict__ W2t,
    const float* __restrict__ b2, const ushort_t* __restrict__ W3t,
    const float* __restrict__ b3, const ushort_t* __restrict__ WqkvT,
    const float* __restrict__ bq, const float* __restrict__ bk, const float* __restrict__ bv,
    float* __restrict__ H3, ushort_t* __restrict__ Qb, ushort_t* __restrict__ Kb,
    ushort_t* __restrict__ VT)
{
  const int wave = threadIdx.x >> 6, lane = threadIdx.x & 63;
  const int ln = lane & 15, g = lane >> 4;
  const int q0 = blockIdx.x * 16;
  const f32x4 zero4 = {0.f, 0.f, 0.f, 0.f};

  __shared__ ushort_t H2ls[16][136];
  __shared__ ushort_t Hls[16][72];

  // gemm2: wave covers cols [wave*32, +32)
  f32x4 a2[2] = {zero4, zero4};
  #pragma unroll 2
  for (int k0 = 0; k0 < 256; k0 += 32) {
    const short8 af = *(const short8*)&H1b[(size_t)(q0 + ln) * 256 + k0 + g * 8];
    const short8 b0 = *(const short8*)&W2t[(size_t)(wave * 32 + ln) * 256 + k0 + g * 8];
    const short8 b1 = *(const short8*)&W2t[(size_t)(wave * 32 + 16 + ln) * 256 + k0 + g * 8];
    a2[0] = __builtin_amdgcn_mfma_f32_16x16x32_bf16(af, b0, a2[0], 0, 0, 0);
    a2[1] = __builtin_amdgcn_mfma_f32_16x16x32_bf16(af, b1, a2[1], 0, 0, 0);
  }
  #pragma unroll
  for (int nt = 0; nt < 2; ++nt)
    #pragma unroll
    for (int r = 0; r < 4; ++r) {
      const int n = wave * 32 + nt * 16 + ln;
      H2ls[4 * g + r][n] = bf16of(fmaxf(a2[nt][r] + b2[n], 0.f));
    }
  __syncthreads();

  // gemm3: wave covers cols [wave*16, +16)
  f32x4 a3 = zero4;
  #pragma unroll
  for (int k0 = 0; k0 < 128; k0 += 32) {
    const short8 af = *(const short8*)&H2ls[ln][k0 + g * 8];
    const short8 bfr = *(const short8*)&W3t[(size_t)(wave * 16 + ln) * 128 + k0 + g * 8];
    a3 = __builtin_amdgcn_mfma_f32_16x16x32_bf16(af, bfr, a3, 0, 0, 0);
  }
  #pragma unroll
  for (int r = 0; r < 4; ++r) {
    const int m = q0 + 4 * g + r;
    const int n = wave * 16 + ln;
    float v = fmaxf(a3[r] + b3[n], 0.f);
    H3[(size_t)m * 64 + n] = v;
    Hls[4 * g + r][n] = bf16of(v);
  }
  __syncthreads();

  // qkv: wave w handles nt set: w0:{0,1}, w1:{2}, w2:{3}, w3:{4}
  const int ntA = (wave == 0) ? 0 : (wave + 1);
  f32x4 accA = zero4, accB = zero4;
  #pragma unroll
  for (int k0 = 0; k0 < 64; k0 += 32) {
    const short8 af = *(const short8*)&Hls[ln][k0 + g * 8];
    const short8 bA = *(const short8*)&WqkvT[(size_t)(ntA * 16 + ln) * 64 + k0 + g * 8];
    accA = __builtin_amdgcn_mfma_f32_16x16x32_bf16(af, bA, accA, 0, 0, 0);
    if (wave == 0) {
      const short8 bB = *(const short8*)&WqkvT[(size_t)(16 + ln) * 64 + k0 + g * 8];
      accB = __builtin_amdgcn_mfma_f32_16x16x32_bf16(af, bB, accB, 0, 0, 0);
    }
  }
  if (wave == 0) {
    const float b0 = (ln < 8) ? bq[ln] : bk[ln - 8];
    #pragma unroll
    for (int r = 0; r < 4; ++r) {
      const int m = q0 + 4 * g + r;
      const float v = accA[r] + b0;
      if (ln < 8) Qb[(size_t)m * 8 + ln] = bf16of(v);
      else        Kb[(size_t)m * 8 + (ln - 8)] = bf16of(v);
    }
    const int d = ln;
    const float bb = bv[d];
    uint2 o;
    o.x = bfpair(accB[0] + bb, accB[1] + bb);
    o.y = bfpair(accB[2] + bb, accB[3] + bb);
    *(uint2*)&VT[(size_t)d * 8192 + q0 + 4 * g] = o;
  } else {
    const int d = (ntA - 1) * 16 + ln;
    const float bb = bv[d];
    uint2 o;
    o.x = bfpair(accA[0] + bb, accA[1] + bb);
    o.y = bfpair(accA[2] + bb, accA[3] + bb);
    *(uint2*)&VT[(size_t)d * 8192 + q0 + 4 * g] = o;
  }
}

// ---------------- attention pass 1 (R11-verified, unchanged) ----------------
__global__ __launch_bounds__(1024) void attn_part_k(
    const ushort_t* __restrict__ Qb, const ushort_t* __restrict__ Kb,
    const ushort_t* __restrict__ VT, float* __restrict__ Pnum,
    float* __restrict__ Pden)
{
  const int tid = threadIdx.x;
  const int wave = tid >> 6, lane = tid & 63;
  const int m = lane & 15, g = lane >> 4;
  const int qg = blockIdx.x >> 3, js = blockIdx.x & 7;
  const int q0 = qg * 256 + wave * 16;
  const int j0 = js * 1024;
  const f32x4 zero4 = {0.f,0.f,0.f,0.f};

  __shared__ ushort_t Vls[2][64][68];
  __shared__ ushort_t Kls[2][64][12];

  const bool isV = (tid < 512);
  const int vd = tid >> 3, vc = tid & 7;
  const bool isK = (tid >= 512 && tid < 576);
  const int kj = tid - 512;

  short8 vreg = {0,0,0,0,0,0,0,0}, kreg = {0,0,0,0,0,0,0,0};
  auto LOAD = [&](int jb) {
    if (isV) vreg = *(const short8*)&VT[(size_t)vd * 8192 + jb + vc * 8];
    if (isK) kreg = *(const short8*)&Kb[(size_t)(jb + kj) * 8];
  };
  auto WRITE = [&](int cur) {
    if (isV) *(short8*)&Vls[cur][vd][vc * 8] = vreg;
    if (isK) *(short8*)&Kls[cur][kj][0] = kreg;
  };

  short8 qf = {0,0,0,0,0,0,0,0};
  if (lane < 16) qf = *(const short8*)&Qb[(size_t)(q0 + m) * 8];

  f32x4 acc[4];
  #pragma unroll
  for (int dt=0;dt<4;dt++) acc[dt] = zero4;
  float lsum = 0.f;

  LOAD(j0);
  int cur = 0;
  for (int it = 0; it < 16; ++it) {
    WRITE(cur);
    __syncthreads();
    if (it + 1 < 16) LOAD(j0 + (it + 1) * 64);

    #pragma unroll
    for (int half = 0; half < 2; ++half) {
      short8 kf0 = {0,0,0,0,0,0,0,0}, kf1 = {0,0,0,0,0,0,0,0};
      if (lane < 16) {
        kf0 = *(const short8*)&Kls[cur][half*32 + m][0];
        kf1 = *(const short8*)&Kls[cur][half*32 + 16 + m][0];
      }
      const f32x4 s0 = __builtin_amdgcn_mfma_f32_16x16x32_bf16(kf0, qf, zero4, 0,0,0);
      const f32x4 s1 = __builtin_amdgcn_mfma_f32_16x16x32_bf16(kf1, qf, zero4, 0,0,0);
      const float e00 = __expf(s0[0]), e01 = __expf(s0[1]), e02 = __expf(s0[2]), e03 = __expf(s0[3]);
      const float e10 = __expf(s1[0]), e11 = __expf(s1[1]), e12 = __expf(s1[2]), e13 = __expf(s1[3]);
      lsum += ((e00+e01)+(e02+e03)) + ((e10+e11)+(e12+e13));
      unsigned X01 = bfpair(e00,e01), X23 = bfpair(e02,e03);
      unsigned Y01 = bfpair(e10,e11), Y23 = bfpair(e12,e13);
      permswap32(X01, Y01); permswap16(X01, Y01);
      permswap32(X23, Y23); permswap16(X23, Y23);
      union { unsigned u[4]; short8 s; } pfu;
      pfu.u[0] = X01;
      pfu.u[1] = X23;
      pfu.u[2] = Y01;
      pfu.u[3] = Y23;
      #pragma unroll
      for (int dt=0;dt<4;dt++) {
        const short8 vf = *(const short8*)&Vls[cur][dt*16 + m][half*32 + g * 8];
        acc[dt] = __builtin_amdgcn_mfma_f32_16x16x32_bf16(pfu.s, vf, acc[dt], 0,0,0);
      }
    }
    cur ^= 1;
  }

  lsum += __shfl_xor(lsum, 16, 64);
  lsum += __shfl_xor(lsum, 32, 64);

  float* np = &Pnum[((size_t)blockIdx.x * 256 + wave * 16) * 64];
  #pragma unroll
  for (int dt=0;dt<4;dt++)
    #pragma unroll
    for (int r=0;r<4;r++)
      np[(size_t)(4*g + r) * 64 + dt*16 + m] = acc[dt][r];
  if (lane < 16)
    Pden[(size_t)blockIdx.x * 256 + wave * 16 + m] = lsum;
}

// ---------------- fused epilogue: merge + residual + MIL scores + pool partials ----------------
// grid 128 x 256 thr; wave owns 16 q rows. Same-wave LDS tiles (no barrier needed
// until the cross-wave pool reduce).
__global__ __launch_bounds__(256) void epilogue_k(
    const float* __restrict__ Pnum, const float* __restrict__ Pden,
    const float* __restrict__ H3, const float* __restrict__ gamma,
    const ushort_t* __restrict__ Wa1t, const float* __restrict__ ba1,
    const float* __restrict__ Wa2, const float* __restrict__ ba2,
    float* __restrict__ pM, float* __restrict__ pS)
{
  const int wave = threadIdx.x >> 6, lane = threadIdx.x & 63;
  const int ln = lane & 15, g = lane >> 4;
  const int q0 = blockIdx.x * 64 + wave * 16;
  const f32x4 zero4 = {0.f, 0.f, 0.f, 0.f};

  __shared__ float Hals[4][16][68];
  __shared__ ushort_t Habls[4][16][72];
  __shared__ float scls[4][16];
  __shared__ float Ms[4][64];
  __shared__ float Ss[4];

  const float gm = gamma[0];
  // merge the wave's 16 rows
  #pragma unroll 4
  for (int r = 0; r < 16; ++r) {
    const int q = q0 + r;
    const int qg = q >> 8, qloc = q & 255;
    float num = 0.f, den = 0.f;
    #pragma unroll
    for (int js = 0; js < 8; ++js) {
      const size_t base = (size_t)(qg * 8 + js) * 256 + qloc;
      num += Pnum[base * 64 + lane];
      den += Pden[base];
    }
    const float hv = fmaf(gm, num / den, H3[(size_t)q * 64 + lane]);
    Hals[wave][r][lane] = hv;
    Habls[wave][r][lane] = bf16of(hv);
  }

  // MIL scores for the wave's 16 rows (same-wave LDS RAW: program order suffices)
  f32x4 acc[4];
  #pragma unroll
  for (int nt = 0; nt < 4; ++nt) acc[nt] = zero4;
  #pragma unroll
  for (int k0 = 0; k0 < 64; k0 += 32) {
    const short8 af = *(const short8*)&Habls[wave][ln][k0 + g * 8];
    #pragma unroll
    for (int nt = 0; nt < 4; ++nt) {
      const short8 bfr = *(const short8*)&Wa1t[(size_t)(nt * 16 + ln) * 64 + k0 + g * 8];
      acc[nt] = __builtin_amdgcn_mfma_f32_16x16x32_bf16(af, bfr, acc[nt], 0, 0, 0);
    }
  }
  #pragma unroll
  for (int r = 0; r < 4; ++r) {
    float s = 0.f;
    #pragma unroll
    for (int nt = 0; nt < 4; ++nt) {
      const int n = nt * 16 + ln;
      s += tanhf(acc[nt][r] + ba1[n]) * Wa2[n];
    }
    s += __shfl_xor(s, 1, 64); s += __shfl_xor(s, 2, 64);
    s += __shfl_xor(s, 4, 64); s += __shfl_xor(s, 8, 64);
    if (ln == 0) scls[wave][4 * g + r] = s + ba2[0];
  }

  // pool partials for the wave's 16 rows
  float macc = 0.f, se = 0.f;
  #pragma unroll 4
  for (int r = 0; r < 16; ++r) {
    const float e = __expf(scls[wave][r]);
    se += e;
    macc = fmaf(e, Hals[wave][r][lane], macc);
  }
  Ms[wave][lane] = macc;
  if (lane == 0) Ss[wave] = se;
  __syncthreads();
  if (wave == 0) {
    pM[(size_t)blockIdx.x * 64 + lane] = Ms[0][lane] + Ms[1][lane] + Ms[2][lane] + Ms[3][lane];
    if (lane == 0) pS[blockIdx.x] = Ss[0] + Ss[1] + Ss[2] + Ss[3];
  }
}

// ---------------- pooling stage 2 (128 partials) ----------------
__global__ void pool2_k(const float* __restrict__ pM, const float* __restrict__ pS,
                        const float* __restrict__ Wc, const float* __restrict__ bc,
                        float* __restrict__ out)
{
  const int lane = threadIdx.x;
  float s_ = pS[lane] + pS[64 + lane];
  s_ += __shfl_xor(s_,1,64);  s_ += __shfl_xor(s_,2,64);
  s_ += __shfl_xor(s_,4,64);  s_ += __shfl_xor(s_,8,64);
  s_ += __shfl_xor(s_,16,64); s_ += __shfl_xor(s_,32,64);
  float m_ = 0.f;
  for (int b = 0; b < 128; ++b) m_ += pM[b * 64 + lane];
  const float Md = m_ / s_;
  out[1 + lane] = Md;
  float yp = Md * Wc[lane];
  yp += __shfl_xor(yp,1,64);  yp += __shfl_xor(yp,2,64);
  yp += __shfl_xor(yp,4,64);  yp += __shfl_xor(yp,8,64);
  yp += __shfl_xor(yp,16,64); yp += __shfl_xor(yp,32,64);
  if (lane == 0) {
    float y = 1.f/(1.f + __expf(-(yp + bc[0])));
    y = fminf(fmaxf(y, 1e-5f), 1.f - 1e-5f);
    out[0] = y;
  }
}

extern "C" void kernel_launch(void* const* d_in, const int* in_sizes, int n_in,
                              void* d_out, int out_size, void* d_ws, size_t ws_size,
                              hipStream_t stream)
{
  const float* x    = (const float*)d_in[0];
  const float* W1   = (const float*)d_in[1];
  const float* b1   = (const float*)d_in[2];
  const float* W2   = (const float*)d_in[3];
  const float* b2   = (const float*)d_in[4];
  const float* W3   = (const float*)d_in[5];
  const float* b3   = (const float*)d_in[6];
  const float* Wq   = (const float*)d_in[7];
  const float* bq   = (const float*)d_in[8];
  const float* Wk   = (const float*)d_in[9];
  const float* bk   = (const float*)d_in[10];
  const float* Wv   = (const float*)d_in[11];
  const float* bv   = (const float*)d_in[12];
  const float* gam  = (const float*)d_in[13];
  const float* Wa1  = (const float*)d_in[14];
  const float* ba1  = (const float*)d_in[15];
  const float* Wa2  = (const float*)d_in[16];
  const float* ba2  = (const float*)d_in[17];
  const float* Wc   = (const float*)d_in[18];
  const float* bc   = (const float*)d_in[19];
  float* out = (float*)d_out;

  char* w = (char*)d_ws;
  float* H3 = (float*)w;        w += (size_t)8192*64*4;
  float* pM = (float*)w;        w += 128*64*4;
  float* pS = (float*)w;        w += 128*4;
  float* Pnum = (float*)w;      w += (size_t)256*256*64*4;
  float* Pden = (float*)w;      w += (size_t)256*256*4;
  ushort_t* H1b = (ushort_t*)w; w += (size_t)8192*256*2;
  ushort_t* Qb  = (ushort_t*)w; w += (size_t)8192*8*2;
  ushort_t* Kb  = (ushort_t*)w; w += (size_t)8192*8*2;
  ushort_t* VT  = (ushort_t*)w; w += (size_t)64*8192*2;
  ushort_t* W1t = (ushort_t*)w; w += (size_t)256*1024*2;
  ushort_t* W2t = (ushort_t*)w; w += (size_t)128*256*2;
  ushort_t* W3t = (ushort_t*)w; w += (size_t)64*128*2;
  ushort_t* Wa1t= (ushort_t*)w; w += (size_t)64*64*2;
  ushort_t* Wqkv= (ushort_t*)w; w += (size_t)80*64*2;

  prep_all_k<<<301, 256, 0, stream>>>(W1, W1t, W2, W2t, W3, W3t, Wa1, Wa1t,
                                      Wq, Wk, Wv, Wqkv);
  gemm_staged<1024,256,16,true ,0><<<256, 1024, 0, stream>>>(x, W1t, b1, H1b, nullptr);
  mlp23_qkv_k<<<512, 256, 0, stream>>>(H1b, W2t, b2, W3t, b3, Wqkv,
                                       bq, bk, bv, H3, Qb, Kb, VT);
  attn_part_k<<<256, 1024, 0, stream>>>(Qb, Kb, VT, Pnum, Pden);
  epilogue_k<<<128, 256, 0, stream>>>(Pnum, Pden, H3, gam, Wa1t, ba1, Wa2, ba2, pM, pS);
  pool2_k<<<1, 64, 0, stream>>>(pM, pS, Wc, bc, out);
}

// Round 13
// 77.795 us; speedup vs baseline: 1.6716x; 1.0155x over previous
//
#include <hip/hip_runtime.h>
#include <math.h>

typedef unsigned short ushort_t;
typedef __attribute__((ext_vector_type(8))) short short8;
typedef __attribute__((ext_vector_type(4))) float f32x4;

__device__ inline unsigned bfpair(float lo, float hi) {
  unsigned r;
  asm("v_cvt_pk_bf16_f32 %0, %1, %2" : "=v"(r) : "v"(lo), "v"(hi));
  return r;
}
__device__ inline ushort_t bf16of(float v) { return (ushort_t)(bfpair(v, v) & 0xffffu); }
__device__ inline void permswap32(unsigned &a, unsigned &b) {
  asm("v_permlane32_swap_b32 %0, %1" : "+v"(a), "+v"(b));
}
__device__ inline void permswap16(unsigned &a, unsigned &b) {
  asm("v_permlane16_swap_b32 %0, %1" : "+v"(a), "+v"(b));
}

// ---------------- fused prep (R11-verified) ----------------
__device__ void transpose_tile(const float* __restrict__ W, ushort_t* __restrict__ Wt,
                               int K, int N, int bx, int by, int t)
{
  __shared__ float Ls[32][33];
  const int n0 = bx * 32, k0 = by * 32;
  const int tx = t & 31, tyb = t >> 5;
  #pragma unroll
  for (int s = 0; s < 4; ++s) {
    const int k = tyb + s * 8;
    Ls[k][tx] = W[(size_t)(k0 + k) * N + n0 + tx];
  }
  __syncthreads();
  #pragma unroll
  for (int s = 0; s < 2; ++s) {
    const int idx = t + 256 * s;
    const int n = idx >> 4, kk = (idx & 15) * 2;
    const unsigned pk = bfpair(Ls[kk][n], Ls[kk + 1][n]);
    *(unsigned*)&Wt[(size_t)(n0 + n) * K + k0 + kk] = pk;
  }
}

__global__ __launch_bounds__(256) void prep_all_k(
    const float* __restrict__ W1, ushort_t* __restrict__ W1t,
    const float* __restrict__ W2, ushort_t* __restrict__ W2t,
    const float* __restrict__ W3, ushort_t* __restrict__ W3t,
    const float* __restrict__ Wa1, ushort_t* __restrict__ Wa1t,
    const float* __restrict__ Wq, const float* __restrict__ Wk,
    const float* __restrict__ Wv, ushort_t* __restrict__ WqkvT)
{
  const int bid = blockIdx.x;
  const int t = threadIdx.x;
  if (bid < 256)      { transpose_tile(W1, W1t, 1024, 256, bid & 7, bid >> 3, t); }
  else if (bid < 288) { const int l = bid - 256; transpose_tile(W2, W2t, 256, 128, l & 3, l >> 2, t); }
  else if (bid < 296) { const int l = bid - 288; transpose_tile(W3, W3t, 128,  64, l & 1, l >> 1, t); }
  else if (bid < 300) { const int l = bid - 296; transpose_tile(Wa1, Wa1t, 64,  64, l & 1, l >> 1, t); }
  else {
    for (int e = t; e < 80 * 64; e += 256) {
      const int j = e >> 6, k = e & 63;
      float v;
      if (j < 8)       v = Wq[k * 8 + j];
      else if (j < 16) v = Wk[k * 8 + (j - 8)];
      else             v = Wv[k * 64 + (j - 16)];
      WqkvT[e] = bf16of(v);
    }
  }
}

// ---------------- LDS-staged pipelined bf16 MFMA GEMM (R9-verified) ----------------
template<int K, int N, int WAVES, bool A_FP32, int OMODE>
__global__ __launch_bounds__(WAVES * 64) void gemm_staged(
    const void* __restrict__ Ap, const ushort_t* __restrict__ Wt,
    const float* __restrict__ bias, void* __restrict__ C0, void* __restrict__ C1)
{
  constexpr int BM = 32;
  constexpr int NWN = N / 32;
  constexpr int NK = K / 32;
  constexpr int A_CH = BM * 4;
  constexpr int B_CH = N * 4;
  static_assert(WAVES * 64 == B_CH, "threads must equal B chunk count");
  static_assert(A_CH <= WAVES * 64, "");

  const int tid = threadIdx.x;
  const int wave = tid >> 6, lane = tid & 63;
  const int ln = lane & 15, g = lane >> 4;
  const int wm = wave / NWN, wn = wave % NWN;
  const int bm0 = blockIdx.x * BM;

  __shared__ ushort_t Als[2][BM][40];
  __shared__ ushort_t Bls[2][N][40];

  const float* Af = (const float*)Ap;
  const ushort_t* Ab = (const ushort_t*)Ap;

  const bool hasA = (tid < A_CH);
  const int arow = tid >> 2, akq = tid & 3;
  const int bc = hasA ? (B_CH - A_CH + tid) : (tid - A_CH);
  const int brow = bc >> 2, bkq = bc & 3;

  float4 rf0, rf1;
  short8 ra, rb;

  auto LOADK = [&](int ks) {
    const int k0 = ks * 32;
    if (hasA) {
      if (A_FP32) {
        const float* src = &Af[(size_t)(bm0 + arow) * K + k0 + akq * 8];
        rf0 = *(const float4*)src;
        rf1 = *(const float4*)(src + 4);
      } else {
        ra = *(const short8*)&Ab[(size_t)(bm0 + arow) * K + k0 + akq * 8];
      }
    }
    rb = *(const short8*)&Wt[(size_t)brow * K + k0 + bkq * 8];
  };
  auto WRITEK = [&](int cur) {
    if (hasA) {
      short8 wa;
      if (A_FP32) {
        union { unsigned u[4]; short8 s8; } cv;
        cv.u[0] = bfpair(rf0.x, rf0.y);
        cv.u[1] = bfpair(rf0.z, rf0.w);
        cv.u[2] = bfpair(rf1.x, rf1.y);
        cv.u[3] = bfpair(rf1.z, rf1.w);
        wa = cv.s8;
      } else {
        wa = ra;
      }
      *(short8*)&Als[cur][arow][akq * 8] = wa;
    }
    *(short8*)&Bls[cur][brow][bkq * 8] = rb;
  };

  f32x4 acc0 = {0.f, 0.f, 0.f, 0.f};
  f32x4 acc1 = {0.f, 0.f, 0.f, 0.f};

  LOADK(0);
  int cur = 0;
  for (int ks = 0; ks < NK; ++ks) {
    WRITEK(cur);
    __syncthreads();
    if (ks + 1 < NK) LOADK(ks + 1);
    const short8 af = *(const short8*)&Als[cur][wm * 16 + ln][g * 8];
    const short8 b0 = *(const short8*)&Bls[cur][wn * 32 + ln][g * 8];
    const short8 b1 = *(const short8*)&Bls[cur][wn * 32 + 16 + ln][g * 8];
    acc0 = __builtin_amdgcn_mfma_f32_16x16x32_bf16(af, b0, acc0, 0, 0, 0);
    acc1 = __builtin_amdgcn_mfma_f32_16x16x32_bf16(af, b1, acc1, 0, 0, 0);
    cur ^= 1;
  }

  #pragma unroll
  for (int nt = 0; nt < 2; ++nt) {
    const f32x4 a = nt ? acc1 : acc0;
    #pragma unroll
    for (int r = 0; r < 4; ++r) {
      const int m = bm0 + wm * 16 + 4 * g + r;
      const int n = wn * 32 + nt * 16 + ln;
      float v = a[r] + bias[n];
      v = fmaxf(v, 0.f);
      if (OMODE == 0) {
        ((ushort_t*)C0)[(size_t)m * N + n] = bf16of(v);
      } else {
        ((float*)C0)[(size_t)m * N + n] = v;
      }
    }
  }
}

// ---------------- fused gemm2 + gemm3 + QKV (R12-verified) ----------------
__global__ __launch_bounds__(256) void mlp23_qkv_k(
    const ushort_t* __restrict__ H1b, const ushort_t* __restrict__ W2t,
    const float* __restrict__ b2, const ushort_t* __restrict__ W3t,
    const float* __restrict__ b3, const ushort_t* __restrict__ WqkvT,
    const float* __restrict__ bq, const float* __restrict__ bk, const float* __restrict__ bv,
    float* __restrict__ H3, ushort_t* __restrict__ Qb, ushort_t* __restrict__ Kb,
    ushort_t* __restrict__ VT)
{
  const int wave = threadIdx.x >> 6, lane = threadIdx.x & 63;
  const int ln = lane & 15, g = lane >> 4;
  const int q0 = blockIdx.x * 16;
  const f32x4 zero4 = {0.f, 0.f, 0.f, 0.f};

  __shared__ ushort_t H2ls[16][136];
  __shared__ ushort_t Hls[16][72];

  f32x4 a2[2] = {zero4, zero4};
  #pragma unroll 2
  for (int k0 = 0; k0 < 256; k0 += 32) {
    const short8 af = *(const short8*)&H1b[(size_t)(q0 + ln) * 256 + k0 + g * 8];
    const short8 b0 = *(const short8*)&W2t[(size_t)(wave * 32 + ln) * 256 + k0 + g * 8];
    const short8 b1 = *(const short8*)&W2t[(size_t)(wave * 32 + 16 + ln) * 256 + k0 + g * 8];
    a2[0] = __builtin_amdgcn_mfma_f32_16x16x32_bf16(af, b0, a2[0], 0, 0, 0);
    a2[1] = __builtin_amdgcn_mfma_f32_16x16x32_bf16(af, b1, a2[1], 0, 0, 0);
  }
  #pragma unroll
  for (int nt = 0; nt < 2; ++nt)
    #pragma unroll
    for (int r = 0; r < 4; ++r) {
      const int n = wave * 32 + nt * 16 + ln;
      H2ls[4 * g + r][n] = bf16of(fmaxf(a2[nt][r] + b2[n], 0.f));
    }
  __syncthreads();

  f32x4 a3 = zero4;
  #pragma unroll
  for (int k0 = 0; k0 < 128; k0 += 32) {
    const short8 af = *(const short8*)&H2ls[ln][k0 + g * 8];
    const short8 bfr = *(const short8*)&W3t[(size_t)(wave * 16 + ln) * 128 + k0 + g * 8];
    a3 = __builtin_amdgcn_mfma_f32_16x16x32_bf16(af, bfr, a3, 0, 0, 0);
  }
  #pragma unroll
  for (int r = 0; r < 4; ++r) {
    const int m = q0 + 4 * g + r;
    const int n = wave * 16 + ln;
    float v = fmaxf(a3[r] + b3[n], 0.f);
    H3[(size_t)m * 64 + n] = v;
    Hls[4 * g + r][n] = bf16of(v);
  }
  __syncthreads();

  const int ntA = (wave == 0) ? 0 : (wave + 1);
  f32x4 accA = zero4, accB = zero4;
  #pragma unroll
  for (int k0 = 0; k0 < 64; k0 += 32) {
    const short8 af = *(const short8*)&Hls[ln][k0 + g * 8];
    const short8 bA = *(const short8*)&WqkvT[(size_t)(ntA * 16 + ln) * 64 + k0 + g * 8];
    accA = __builtin_amdgcn_mfma_f32_16x16x32_bf16(af, bA, accA, 0, 0, 0);
    if (wave == 0) {
      const short8 bB = *(const short8*)&WqkvT[(size_t)(16 + ln) * 64 + k0 + g * 8];
      accB = __builtin_amdgcn_mfma_f32_16x16x32_bf16(af, bB, accB, 0, 0, 0);
    }
  }
  if (wave == 0) {
    const float b0 = (ln < 8) ? bq[ln] : bk[ln - 8];
    #pragma unroll
    for (int r = 0; r < 4; ++r) {
      const int m = q0 + 4 * g + r;
      const float v = accA[r] + b0;
      if (ln < 8) Qb[(size_t)m * 8 + ln] = bf16of(v);
      else        Kb[(size_t)m * 8 + (ln - 8)] = bf16of(v);
    }
    const int d = ln;
    const float bb = bv[d];
    uint2 o;
    o.x = bfpair(accB[0] + bb, accB[1] + bb);
    o.y = bfpair(accB[2] + bb, accB[3] + bb);
    *(uint2*)&VT[(size_t)d * 8192 + q0 + 4 * g] = o;
  } else {
    const int d = (ntA - 1) * 16 + ln;
    const float bb = bv[d];
    uint2 o;
    o.x = bfpair(accA[0] + bb, accA[1] + bb);
    o.y = bfpair(accA[2] + bb, accA[3] + bb);
    *(uint2*)&VT[(size_t)d * 8192 + q0 + 4 * g] = o;
  }
}

// ---------------- attention pass 1 (R11-verified; XCD-aligned index decode) ----------------
// blockIdx = js*32 + qg  ->  XCD(blockIdx%8) == qg%8, matching epilogue reader.
__global__ __launch_bounds__(1024) void attn_part_k(
    const ushort_t* __restrict__ Qb, const ushort_t* __restrict__ Kb,
    const ushort_t* __restrict__ VT, float* __restrict__ Pnum,
    float* __restrict__ Pden)
{
  const int tid = threadIdx.x;
  const int wave = tid >> 6, lane = tid & 63;
  const int m = lane & 15, g = lane >> 4;
  const int qg = blockIdx.x & 31, js = blockIdx.x >> 5;
  const int q0 = qg * 256 + wave * 16;
  const int j0 = js * 1024;
  const f32x4 zero4 = {0.f,0.f,0.f,0.f};

  __shared__ ushort_t Vls[2][64][68];
  __shared__ ushort_t Kls[2][64][12];

  const bool isV = (tid < 512);
  const int vd = tid >> 3, vc = tid & 7;
  const bool isK = (tid >= 512 && tid < 576);
  const int kj = tid - 512;

  short8 vreg = {0,0,0,0,0,0,0,0}, kreg = {0,0,0,0,0,0,0,0};
  auto LOAD = [&](int jb) {
    if (isV) vreg = *(const short8*)&VT[(size_t)vd * 8192 + jb + vc * 8];
    if (isK) kreg = *(const short8*)&Kb[(size_t)(jb + kj) * 8];
  };
  auto WRITE = [&](int cur) {
    if (isV) *(short8*)&Vls[cur][vd][vc * 8] = vreg;
    if (isK) *(short8*)&Kls[cur][kj][0] = kreg;
  };

  short8 qf = {0,0,0,0,0,0,0,0};
  if (lane < 16) qf = *(const short8*)&Qb[(size_t)(q0 + m) * 8];

  f32x4 acc[4];
  #pragma unroll
  for (int dt=0;dt<4;dt++) acc[dt] = zero4;
  float lsum = 0.f;

  LOAD(j0);
  int cur = 0;
  for (int it = 0; it < 16; ++it) {
    WRITE(cur);
    __syncthreads();
    if (it + 1 < 16) LOAD(j0 + (it + 1) * 64);

    #pragma unroll
    for (int half = 0; half < 2; ++half) {
      short8 kf0 = {0,0,0,0,0,0,0,0}, kf1 = {0,0,0,0,0,0,0,0};
      if (lane < 16) {
        kf0 = *(const short8*)&Kls[cur][half*32 + m][0];
        kf1 = *(const short8*)&Kls[cur][half*32 + 16 + m][0];
      }
      const f32x4 s0 = __builtin_amdgcn_mfma_f32_16x16x32_bf16(kf0, qf, zero4, 0,0,0);
      const f32x4 s1 = __builtin_amdgcn_mfma_f32_16x16x32_bf16(kf1, qf, zero4, 0,0,0);
      const float e00 = __expf(s0[0]), e01 = __expf(s0[1]), e02 = __expf(s0[2]), e03 = __expf(s0[3]);
      const float e10 = __expf(s1[0]), e11 = __expf(s1[1]), e12 = __expf(s1[2]), e13 = __expf(s1[3]);
      lsum += ((e00+e01)+(e02+e03)) + ((e10+e11)+(e12+e13));
      unsigned X01 = bfpair(e00,e01), X23 = bfpair(e02,e03);
      unsigned Y01 = bfpair(e10,e11), Y23 = bfpair(e12,e13);
      permswap32(X01, Y01); permswap16(X01, Y01);
      permswap32(X23, Y23); permswap16(X23, Y23);
      union { unsigned u[4]; short8 s; } pfu;
      pfu.u[0] = X01;
      pfu.u[1] = X23;
      pfu.u[2] = Y01;
      pfu.u[3] = Y23;
      #pragma unroll
      for (int dt=0;dt<4;dt++) {
        const short8 vf = *(const short8*)&Vls[cur][dt*16 + m][half*32 + g * 8];
        acc[dt] = __builtin_amdgcn_mfma_f32_16x16x32_bf16(pfu.s, vf, acc[dt], 0,0,0);
      }
    }
    cur ^= 1;
  }

  lsum += __shfl_xor(lsum, 16, 64);
  lsum += __shfl_xor(lsum, 32, 64);

  float* np = &Pnum[((size_t)blockIdx.x * 256 + wave * 16) * 64];
  #pragma unroll
  for (int dt=0;dt<4;dt++)
    #pragma unroll
    for (int r=0;r<4;r++)
      np[(size_t)(4*g + r) * 64 + dt*16 + m] = acc[dt][r];
  if (lane < 16)
    Pden[(size_t)blockIdx.x * 256 + wave * 16 + m] = lsum;
}

// ---------------- fused epilogue: merge + residual + MIL + pool partials ----------------
// grid 512 (2 blocks/CU), block 256. e = sub*32 + qg -> XCD(e%8)==qg%8 matches
// attn_part writer -> Pnum slice is L2-resident. Wave merges 4 rows (32 loads);
// MIL MFMA computed redundantly per wave (each wave holds all 16 scores itself).
__global__ __launch_bounds__(256) void epilogue_k(
    const float* __restrict__ Pnum, const float* __restrict__ Pden,
    const float* __restrict__ H3, const float* __restrict__ gamma,
    const ushort_t* __restrict__ Wa1t, const float* __restrict__ ba1,
    const float* __restrict__ Wa2, const float* __restrict__ ba2,
    float* __restrict__ pM, float* __restrict__ pS)
{
  const int wave = threadIdx.x >> 6, lane = threadIdx.x & 63;
  const int ln = lane & 15, g = lane >> 4;
  const int e = blockIdx.x;
  const int sub = e >> 5, qg = e & 31;
  const int q0 = qg * 256 + sub * 16;
  const f32x4 zero4 = {0.f, 0.f, 0.f, 0.f};

  __shared__ float Hals[16][68];
  __shared__ ushort_t Habls[16][72];
  __shared__ float scls[16];
  __shared__ float Ms[4][64];
  __shared__ float Ss[4];

  const float gm = gamma[0];
  // merge: wave handles rows wave*4 .. wave*4+3
  #pragma unroll
  for (int rr = 0; rr < 4; ++rr) {
    const int r = wave * 4 + rr;
    const int q = q0 + r;
    const int qloc = q & 255;
    float num = 0.f, den = 0.f;
    #pragma unroll
    for (int js = 0; js < 8; ++js) {
      const size_t base = (size_t)(js * 32 + qg) * 256 + qloc;
      num += Pnum[base * 64 + lane];
      den += Pden[base];
    }
    const float hv = fmaf(gm, num / den, H3[(size_t)q * 64 + lane]);
    Hals[r][lane] = hv;
    Habls[r][lane] = bf16of(hv);
  }
  __syncthreads();

  // MIL scores for all 16 rows, redundantly per wave (identical values)
  f32x4 acc[4];
  #pragma unroll
  for (int nt = 0; nt < 4; ++nt) acc[nt] = zero4;
  #pragma unroll
  for (int k0 = 0; k0 < 64; k0 += 32) {
    const short8 af = *(const short8*)&Habls[ln][k0 + g * 8];
    #pragma unroll
    for (int nt = 0; nt < 4; ++nt) {
      const short8 bfr = *(const short8*)&Wa1t[(size_t)(nt * 16 + ln) * 64 + k0 + g * 8];
      acc[nt] = __builtin_amdgcn_mfma_f32_16x16x32_bf16(af, bfr, acc[nt], 0, 0, 0);
    }
  }
  #pragma unroll
  for (int r = 0; r < 4; ++r) {
    float s = 0.f;
    #pragma unroll
    for (int nt = 0; nt < 4; ++nt) {
      const int n = nt * 16 + ln;
      s += tanhf(acc[nt][r] + ba1[n]) * Wa2[n];
    }
    s += __shfl_xor(s, 1, 64); s += __shfl_xor(s, 2, 64);
    s += __shfl_xor(s, 4, 64); s += __shfl_xor(s, 8, 64);
    if (ln == 0) scls[4 * g + r] = s + ba2[0];  // same values from all waves
  }
  // wave wrote all 16 slots itself -> program-order read is safe
  float macc = 0.f, se = 0.f;
  #pragma unroll
  for (int rr = 0; rr < 4; ++rr) {
    const int r = wave * 4 + rr;
    const float ee = __expf(scls[r]);
    se += ee;
    macc = fmaf(ee, Hals[r][lane], macc);
  }
  Ms[wave][lane] = macc;
  if (lane == 0) Ss[wave] = se;
  __syncthreads();
  if (wave == 0) {
    pM[(size_t)e * 64 + lane] = Ms[0][lane] + Ms[1][lane] + Ms[2][lane] + Ms[3][lane];
    if (lane == 0) pS[e] = Ss[0] + Ss[1] + Ss[2] + Ss[3];
  }
}

// ---------------- pooling stage 2 (512 partials, 16 waves) ----------------
__global__ __launch_bounds__(1024) void pool2_k(
    const float* __restrict__ pM, const float* __restrict__ pS,
    const float* __restrict__ Wc, const float* __restrict__ bc,
    float* __restrict__ out)
{
  const int wave = threadIdx.x >> 6, lane = threadIdx.x & 63;
  __shared__ float Ms2[16][64];
  __shared__ float Ss2[16];
  float m_ = 0.f;
  #pragma unroll
  for (int i = 0; i < 32; ++i)
    m_ += pM[(size_t)(wave * 32 + i) * 64 + lane];
  Ms2[wave][lane] = m_;
  float s_ = (lane < 32) ? pS[wave * 32 + lane] : 0.f;
  s_ += __shfl_xor(s_, 1, 64);  s_ += __shfl_xor(s_, 2, 64);
  s_ += __shfl_xor(s_, 4, 64);  s_ += __shfl_xor(s_, 8, 64);
  s_ += __shfl_xor(s_, 16, 64); s_ += __shfl_xor(s_, 32, 64);
  if (lane == 0) Ss2[wave] = s_;
  __syncthreads();
  if (wave == 0) {
    float mm = 0.f, ss = 0.f;
    #pragma unroll
    for (int i = 0; i < 16; ++i) { mm += Ms2[i][lane]; ss += Ss2[i]; }
    const float Md = mm / ss;
    out[1 + lane] = Md;
    float yp = Md * Wc[lane];
    yp += __shfl_xor(yp, 1, 64);  yp += __shfl_xor(yp, 2, 64);
    yp += __shfl_xor(yp, 4, 64);  yp += __shfl_xor(yp, 8, 64);
    yp += __shfl_xor(yp, 16, 64); yp += __shfl_xor(yp, 32, 64);
    if (lane == 0) {
      float y = 1.f / (1.f + __expf(-(yp + bc[0])));
      y = fminf(fmaxf(y, 1e-5f), 1.f - 1e-5f);
      out[0] = y;
    }
  }
}

extern "C" void kernel_launch(void* const* d_in, const int* in_sizes, int n_in,
                              void* d_out, int out_size, void* d_ws, size_t ws_size,
                              hipStream_t stream)
{
  const float* x    = (const float*)d_in[0];
  const float* W1   = (const float*)d_in[1];
  const float* b1   = (const float*)d_in[2];
  const float* W2   = (const float*)d_in[3];
  const float* b2   = (const float*)d_in[4];
  const float* W3   = (const float*)d_in[5];
  const float* b3   = (const float*)d_in[6];
  const float* Wq   = (const float*)d_in[7];
  const float* bq   = (const float*)d_in[8];
  const float* Wk   = (const float*)d_in[9];
  const float* bk   = (const float*)d_in[10];
  const float* Wv   = (const float*)d_in[11];
  const float* bv   = (const float*)d_in[12];
  const float* gam  = (const float*)d_in[13];
  const float* Wa1  = (const float*)d_in[14];
  const float* ba1  = (const float*)d_in[15];
  const float* Wa2  = (const float*)d_in[16];
  const float* ba2  = (const float*)d_in[17];
  const float* Wc   = (const float*)d_in[18];
  const float* bc   = (const float*)d_in[19];
  float* out = (float*)d_out;

  char* w = (char*)d_ws;
  float* H3 = (float*)w;        w += (size_t)8192*64*4;
  float* pM = (float*)w;        w += 512*64*4;
  float* pS = (float*)w;        w += 512*4;
  float* Pnum = (float*)w;      w += (size_t)256*256*64*4;
  float* Pden = (float*)w;      w += (size_t)256*256*4;
  ushort_t* H1b = (ushort_t*)w; w += (size_t)8192*256*2;
  ushort_t* Qb  = (ushort_t*)w; w += (size_t)8192*8*2;
  ushort_t* Kb  = (ushort_t*)w; w += (size_t)8192*8*2;
  ushort_t* VT  = (ushort_t*)w; w += (size_t)64*8192*2;
  ushort_t* W1t = (ushort_t*)w; w += (size_t)256*1024*2;
  ushort_t* W2t = (ushort_t*)w; w += (size_t)128*256*2;
  ushort_t* W3t = (ushort_t*)w; w += (size_t)64*128*2;
  ushort_t* Wa1t= (ushort_t*)w; w += (size_t)64*64*2;
  ushort_t* Wqkv= (ushort_t*)w; w += (size_t)80*64*2;

  prep_all_k<<<301, 256, 0, stream>>>(W1, W1t, W2, W2t, W3, W3t, Wa1, Wa1t,
                                      Wq, Wk, Wv, Wqkv);
  gemm_staged<1024,256,16,true ,0><<<256, 1024, 0, stream>>>(x, W1t, b1, H1b, nullptr);
  mlp23_qkv_k<<<512, 256, 0, stream>>>(H1b, W2t, b2, W3t, b3, Wqkv,
                                       bq, bk, bv, H3, Qb, Kb, VT);
  attn_part_k<<<256, 1024, 0, stream>>>(Qb, Kb, VT, Pnum, Pden);
  epilogue_k<<<512, 256, 0, stream>>>(Pnum, Pden, H3, gam, Wa1t, ba1, Wa2, ba2, pM, pS);
  pool2_k<<<1, 1024, 0, stream>>>(pM, pS, Wc, bc, out);
}